// Round 6
// baseline (432.551 us; speedup 1.0000x reference)
//
#include <hip/hip_runtime.h>
#include <hip/hip_bf16.h>

// Problem: x [B,U,C] fp32, W [1,C,J,S,U] fp32, out [B,J,S,1] fp32.
// Internal compute in packed bf16 (threshold = 2% of max|ref| — bf16 internal
// rounding contributes ~3e-4 absolute, ~7x margin).
#define BB 128
#define UU 8
#define CC 2048
#define JJ 32
#define SS 16

typedef unsigned int u32;
typedef unsigned short u16;

__device__ __forceinline__ float bflo(u32 p) { return __uint_as_float(p << 16); }
__device__ __forceinline__ float bfhi(u32 p) { return __uint_as_float(p & 0xffff0000u); }
// fp32 -> bf16 bits, round-to-nearest-even.
__device__ __forceinline__ u32 f2b(float f) {
    u32 bits = __float_as_uint(f);
    u32 r = bits + 0x7fffu + ((bits >> 16) & 1u);
    return r >> 16;
}
__device__ __forceinline__ u32 pack2(float a, float b) { return f2b(a) | (f2b(b) << 16); }

// ---------------------------------------------------------------------------
// Runtime dtype check (belt-and-suspenders): fp32 words' low-16 bits are
// mantissa noise (~19% in the bf16 N(0,1) exponent band); packed-bf16 words'
// low-16 bits are bf16 values (~100% in band). flag=1 -> bf16.
__global__ __launch_bounds__(256) void k_detect(const u32* __restrict__ p,
                                                int* __restrict__ flag) {
    __shared__ int red[4];
    int t = threadIdx.x;
    int cnt = 0;
    for (int i = t; i < 2048; i += 256) {
        u32 e = (p[i] >> 7) & 0xFF;
        cnt += (e >= 0x60 && e <= 0x8F) ? 1 : 0;
    }
#pragma unroll
    for (int o = 32; o > 0; o >>= 1) cnt += __shfl_down(cnt, o, 64);
    if ((t & 63) == 0) red[t >> 6] = cnt;
    __syncthreads();
    if (t == 0) flag[0] = ((red[0] + red[1] + red[2] + red[3]) > 1228) ? 1 : 0;
}

// ---------------------------------------------------------------------------
// Wb[c][j][s][u] packed bf16 from W (layout already u-fastest).
__global__ __launch_bounds__(256) void k_cast_W(const void* __restrict__ W,
                                                u16* __restrict__ Wb,
                                                const int* __restrict__ flag) {
    int g = blockIdx.x * 256 + threadIdx.x;  // [0, 1048576)
    uint4 p;
    if (*flag) {
        p = ((const uint4*)W)[g];  // already bf16-packed
    } else {
        const float4* W4 = (const float4*)W;
        float4 a = W4[2 * g], b = W4[2 * g + 1];
        p.x = pack2(a.x, a.y);
        p.y = pack2(a.z, a.w);
        p.z = pack2(b.x, b.y);
        p.w = pack2(b.z, b.w);
    }
    ((uint4*)Wb)[g] = p;
}

// ---------------------------------------------------------------------------
// xA[b][c][u] packed bf16 from x[b][u][c].
__global__ __launch_bounds__(256) void k_build_xA(const void* __restrict__ x,
                                                  u16* __restrict__ xA,
                                                  const int* __restrict__ flag) {
    int b = blockIdx.x >> 3;
    int c = (blockIdx.x & 7) * 256 + threadIdx.x;
    uint4 p;
    if (*flag) {
        const u16* xh = (const u16*)x + (size_t)b * UU * CC;
        u16 v[8];
#pragma unroll
        for (int u = 0; u < 8; ++u) v[u] = xh[u * CC + c];
        p.x = (u32)v[0] | ((u32)v[1] << 16);
        p.y = (u32)v[2] | ((u32)v[3] << 16);
        p.z = (u32)v[4] | ((u32)v[5] << 16);
        p.w = (u32)v[6] | ((u32)v[7] << 16);
    } else {
        const float* xf = (const float*)x + (size_t)b * UU * CC;
        float v[8];
#pragma unroll
        for (int u = 0; u < 8; ++u) v[u] = xf[u * CC + c];
        p.x = pack2(v[0], v[1]);
        p.y = pack2(v[2], v[3]);
        p.z = pack2(v[4], v[5]);
        p.w = pack2(v[6], v[7]);
    }
    ((uint4*)xA)[(size_t)b * CC + c] = p;
}

__global__ __launch_bounds__(256) void k_zero(float* __restrict__ p, int n) {
    int i = blockIdx.x * 256 + threadIdx.x;
    if (i < n) p[i] = 0.f;
}

// ---------------------------------------------------------------------------
// Softmax over C for each j; bbp/ccp layout [j][c].
__global__ __launch_bounds__(256) void k_softmax(const float* __restrict__ bbp,
                                                 float* __restrict__ ccp) {
    int j = blockIdx.x, t = threadIdx.x;
    __shared__ float red[4];
    __shared__ float bcast[2];
    const float* row = bbp + j * CC;
    float m = -1e30f;
    for (int c = t; c < CC; c += 256) m = fmaxf(m, row[c]);
#pragma unroll
    for (int o = 32; o > 0; o >>= 1) m = fmaxf(m, __shfl_down(m, o, 64));
    if ((t & 63) == 0) red[t >> 6] = m;
    __syncthreads();
    if (t == 0) bcast[0] = fmaxf(fmaxf(red[0], red[1]), fmaxf(red[2], red[3]));
    __syncthreads();
    float mm = bcast[0];
    float ssum = 0.f;
    for (int c = t; c < CC; c += 256) ssum += expf(row[c] - mm);
#pragma unroll
    for (int o = 32; o > 0; o >>= 1) ssum += __shfl_down(ssum, o, 64);
    if ((t & 63) == 0) red[t >> 6] = ssum;
    __syncthreads();
    if (t == 0) bcast[1] = red[0] + red[1] + red[2] + red[3];
    __syncthreads();
    float inv = 1.0f / bcast[1];
    for (int c = t; c < CC; c += 256) ccp[j * CC + c] = expf(row[c] - mm) * inv;
}

// ---------------------------------------------------------------------------
// Pass A (partial over a c-slice): spart[slice][b][j][s] =
//   sum_{c in slice} cc[j,c] * sum_u W[c,j,s,u] * x[b,u,c]
// Grid 1024 = 32 j * 8 bgroups * 4 slices. Thread (bi<16, si<16) owns ONE
// output -> no cross-lane reduction, no race.
__global__ __launch_bounds__(256) void k_passA(const u16* __restrict__ xA,
                                               const u16* __restrict__ Wb,
                                               const float* __restrict__ ccp,
                                               float* __restrict__ spart) {
    __shared__ uint4 xlds[16 * 65];  // [bi][ci], row stride 65
    __shared__ uint4 wlds[64 * 16];  // [ci][sp]
    __shared__ float ccs[64];
    int j = blockIdx.x & 31;
    int bg = (blockIdx.x >> 5) & 7;
    int slice = blockIdx.x >> 8;
    int b0 = bg * 16;
    int t = threadIdx.x;
    int si = t & 15, bi = t >> 4;
    const uint4* xA4 = (const uint4*)xA;
    const uint4* W4 = (const uint4*)Wb;
    float acc = 0.f;
    for (int ch = 0; ch < 8; ++ch) {
        int c0 = slice * 512 + ch * 64;
#pragma unroll
        for (int r = 0; r < 4; ++r) {  // 1024 uint4 of x
            int q = t + r * 256;
            int bi2 = q >> 6, ci2 = q & 63;
            xlds[bi2 * 65 + ci2] = xA4[(size_t)(b0 + bi2) * CC + c0 + ci2];
        }
#pragma unroll
        for (int r = 0; r < 4; ++r) {  // 1024 uint4 of W
            int q = t + r * 256;
            int ci2 = q >> 4, sp = q & 15;
            wlds[ci2 * 16 + sp] = W4[(size_t)(c0 + ci2) * 512 + j * 16 + sp];
        }
        if (t < 64) ccs[t] = ccp[j * CC + c0 + t];
        __syncthreads();
#pragma unroll 8
        for (int ci = 0; ci < 64; ++ci) {
            uint4 wp = wlds[ci * 16 + si];
            uint4 xp = xlds[bi * 65 + ci];
            float cw = ccs[ci];
            u32 wa[4] = {wp.x, wp.y, wp.z, wp.w};
            u32 xa[4] = {xp.x, xp.y, xp.z, xp.w};
            float d = 0.f;
#pragma unroll
            for (int e = 0; e < 4; ++e) {
                d = fmaf(bflo(wa[e]), bflo(xa[e]), d);
                d = fmaf(bfhi(wa[e]), bfhi(xa[e]), d);
            }
            acc = fmaf(d, cw, acc);
        }
        __syncthreads();
    }
    spart[(size_t)slice * 65536 + (b0 + bi) * 512 + j * 16 + si] = acc;
}

// ---------------------------------------------------------------------------
// Squash: sum the 4 c-slice partials, then norm over J (reference axis=1 of
// [B,J,S]). Output is FP32 (reference output dtype).
__global__ __launch_bounds__(256) void k_squash(const float* __restrict__ spart,
                                                float* __restrict__ v_out,
                                                float* __restrict__ out,
                                                int write_out) {
    int idx = blockIdx.x * 256 + threadIdx.x;  // B*S = 2048
    if (idx >= BB * SS) return;
    int b = idx >> 4, si = idx & 15;
    float s[32];
    float msq = 0.f;
#pragma unroll
    for (int jj = 0; jj < 32; ++jj) {
        int o = b * 512 + jj * 16 + si;
        float v = spart[o] + spart[65536 + o] + spart[2 * 65536 + o] + spart[3 * 65536 + o];
        s[jj] = v;
        msq = fmaf(v, v, msq);
    }
    float scale = msq / ((1.f + msq) * sqrtf(fmaxf(msq, 1e-30f)));
#pragma unroll
    for (int jj = 0; jj < 32; ++jj) {
        float v = s[jj] * scale;
        v_out[b * 512 + jj * 16 + si] = v;
        if (write_out) out[b * 512 + jj * 16 + si] = v;
    }
}

// ---------------------------------------------------------------------------
// Pass B: bb[j][c] += (1/B) sum_{b,s} (sum_u W[c,j,s,u] x[b,u,c]) * v[b,j,s]
// Grid 4096 = 32 j * 128 c-chunks of 16. Thread = (bl<16 b-lanes, ci<16).
__global__ __launch_bounds__(256) void k_passB(const u16* __restrict__ xA,
                                               const u16* __restrict__ Wb,
                                               const float* __restrict__ v_in,
                                               float* __restrict__ bbp) {
    __shared__ uint4 xlds[128 * 17];  // [b][ci] padded
    __shared__ uint4 wlds[16 * 17];   // [ci][sp] padded
    __shared__ float vlds[128 * 17];  // [b][sp] padded
    __shared__ float red[256];
    int j = blockIdx.x & 31;
    int c0 = (blockIdx.x >> 5) * 16;
    int t = threadIdx.x;
    int bl = t & 15, ci = t >> 4;
    const uint4* xA4 = (const uint4*)xA;
    const uint4* W4 = (const uint4*)Wb;
    for (int q = t; q < 2048; q += 256) {
        int b = q >> 4, cix = q & 15;
        xlds[b * 17 + cix] = xA4[(size_t)b * CC + c0 + cix];
    }
    {
        int ci2 = t >> 4, sp = t & 15;
        wlds[ci2 * 17 + sp] = W4[(size_t)(c0 + ci2) * 512 + j * 16 + sp];
    }
    for (int q = t; q < 2048; q += 256) {
        int b = q >> 4, sp = q & 15;
        vlds[b * 17 + sp] = v_in[b * 512 + j * 16 + sp];
    }
    __syncthreads();
    float xv[8][8];
#pragma unroll
    for (int k = 0; k < 8; ++k) {
        uint4 xp = xlds[(bl + k * 16) * 17 + ci];
        u32 a[4] = {xp.x, xp.y, xp.z, xp.w};
#pragma unroll
        for (int e = 0; e < 4; ++e) {
            xv[k][2 * e] = bflo(a[e]);
            xv[k][2 * e + 1] = bfhi(a[e]);
        }
    }
    float acc = 0.f;
#pragma unroll
    for (int sp = 0; sp < 16; ++sp) {
        uint4 wp = wlds[ci * 17 + sp];
        u32 a[4] = {wp.x, wp.y, wp.z, wp.w};
        float wv[8];
#pragma unroll
        for (int e = 0; e < 4; ++e) {
            wv[2 * e] = bflo(a[e]);
            wv[2 * e + 1] = bfhi(a[e]);
        }
#pragma unroll
        for (int k = 0; k < 8; ++k) {
            float d = 0.f;
#pragma unroll
            for (int u = 0; u < 8; ++u) d = fmaf(wv[u], xv[k][u], d);
            acc = fmaf(d, vlds[(bl + k * 16) * 17 + sp], acc);
        }
    }
    red[t] = acc;  // t == ci*16 + bl
    __syncthreads();
    if (t < 16) {
        float ssum = 0.f;
#pragma unroll
        for (int l = 0; l < 16; ++l) ssum += red[t * 16 + l];
        bbp[j * CC + c0 + t] += ssum * (1.0f / BB);
    }
}

// ---------------------------------------------------------------------------
extern "C" void kernel_launch(void* const* d_in, const int* in_sizes, int n_in,
                              void* d_out, int out_size, void* d_ws, size_t ws_size,
                              hipStream_t stream) {
    // Order resolved by element count (x: 2,097,152; W: 8,388,608) — proven a
    // no-op for this harness (in_sizes[0] is x), kept for robustness.
    const void* x = d_in[0];
    const void* W = d_in[1];
    if (in_sizes[0] == CC * JJ * SS * UU) {
        x = d_in[1];
        W = d_in[0];
    }
    float* out = (float*)d_out;  // reference output dtype: fp32

    char* ws = (char*)d_ws;
    u16* Wb = (u16*)ws;                                      // 16 MiB
    u16* xA = (u16*)(ws + (16u << 20));                      // 4 MiB
    float* spart = (float*)(ws + (20u << 20));               // 1 MiB
    float* v_buf = (float*)(ws + (21u << 20));               // 256 KiB
    float* bbp = (float*)(ws + (21u << 20) + 262144);        // 256 KiB
    float* ccp = (float*)(ws + (21u << 20) + 2 * 262144);    // 256 KiB
    int* flags = (int*)(ws + (21u << 20) + 3 * 262144);      // 2 ints

    k_detect<<<1, 256, 0, stream>>>((const u32*)x, flags + 0);
    k_detect<<<1, 256, 0, stream>>>((const u32*)W, flags + 1);
    k_cast_W<<<4096, 256, 0, stream>>>(W, Wb, flags + 1);
    k_build_xA<<<1024, 256, 0, stream>>>(x, xA, flags + 0);
    k_zero<<<256, 256, 0, stream>>>(bbp, CC * JJ);

    for (int it = 0; it < 3; ++it) {
        k_softmax<<<32, 256, 0, stream>>>(bbp, ccp);
        k_passA<<<1024, 256, 0, stream>>>(xA, Wb, ccp, spart);
        k_squash<<<8, 256, 0, stream>>>(spart, v_buf, out, it == 2 ? 1 : 0);
        if (it < 2) k_passB<<<4096, 256, 0, stream>>>(xA, Wb, v_buf, bbp);
    }
}

// Round 7
// 369.040 us; speedup vs baseline: 1.1721x; 1.1721x over previous
//
#include <hip/hip_runtime.h>
#include <hip/hip_bf16.h>

// Problem: x [B,U,C] fp32, W [1,C,J,S,U] fp32, out [B,J,S,1] fp32.
// passA as bf16 MFMA GEMM: s[b,(j,s)] = sum_k xA[b,k] * Bmat[(j,s),k],
// k=(c,u), Bmat = cc[j,c]*W rebuilt per routing iteration.
#define BB 128
#define UU 8
#define CC 2048
#define JJ 32
#define SS 16

typedef unsigned int u32;
typedef unsigned short u16;
typedef __attribute__((ext_vector_type(8))) short bf16x8;
typedef __attribute__((ext_vector_type(4))) float f32x4;

__device__ __forceinline__ float bflo(u32 p) { return __uint_as_float(p << 16); }
__device__ __forceinline__ float bfhi(u32 p) { return __uint_as_float(p & 0xffff0000u); }
// fp32 -> bf16 bits, round-to-nearest-even.
__device__ __forceinline__ u32 f2b(float f) {
    u32 bits = __float_as_uint(f);
    u32 r = bits + 0x7fffu + ((bits >> 16) & 1u);
    return r >> 16;
}
__device__ __forceinline__ u32 pack2(float a, float b) { return f2b(a) | (f2b(b) << 16); }

// ---------------------------------------------------------------------------
// Runtime dtype check (proven: returns 0/fp32 for this harness; kept for
// robustness). flag=1 -> bf16.
__global__ __launch_bounds__(256) void k_detect(const u32* __restrict__ p,
                                                int* __restrict__ flag) {
    __shared__ int red[4];
    int t = threadIdx.x;
    int cnt = 0;
    for (int i = t; i < 2048; i += 256) {
        u32 e = (p[i] >> 7) & 0xFF;
        cnt += (e >= 0x60 && e <= 0x8F) ? 1 : 0;
    }
#pragma unroll
    for (int o = 32; o > 0; o >>= 1) cnt += __shfl_down(cnt, o, 64);
    if ((t & 63) == 0) red[t >> 6] = cnt;
    __syncthreads();
    if (t == 0) flag[0] = ((red[0] + red[1] + red[2] + red[3]) > 1228) ? 1 : 0;
}

// ---------------------------------------------------------------------------
// xA[b][c][u] packed bf16 from x[b][u][c].
__global__ __launch_bounds__(256) void k_build_xA(const void* __restrict__ x,
                                                  u16* __restrict__ xA,
                                                  const int* __restrict__ flag) {
    int b = blockIdx.x >> 3;
    int c = (blockIdx.x & 7) * 256 + threadIdx.x;
    uint4 p;
    if (*flag) {
        const u16* xh = (const u16*)x + (size_t)b * UU * CC;
        u16 v[8];
#pragma unroll
        for (int u = 0; u < 8; ++u) v[u] = xh[u * CC + c];
        p.x = (u32)v[0] | ((u32)v[1] << 16);
        p.y = (u32)v[2] | ((u32)v[3] << 16);
        p.z = (u32)v[4] | ((u32)v[5] << 16);
        p.w = (u32)v[6] | ((u32)v[7] << 16);
    } else {
        const float* xf = (const float*)x + (size_t)b * UU * CC;
        float v[8];
#pragma unroll
        for (int u = 0; u < 8; ++u) v[u] = xf[u * CC + c];
        p.x = pack2(v[0], v[1]);
        p.y = pack2(v[2], v[3]);
        p.z = pack2(v[4], v[5]);
        p.w = pack2(v[6], v[7]);
    }
    ((uint4*)xA)[(size_t)b * CC + c] = p;
}

__global__ __launch_bounds__(256) void k_zero(float* __restrict__ p, int n) {
    int i = blockIdx.x * 256 + threadIdx.x;
    if (i < n) p[i] = 0.f;
}

// ---------------------------------------------------------------------------
// Softmax over C for each j; bbp/ccp layout [j][c].
__global__ __launch_bounds__(256) void k_softmax(const float* __restrict__ bbp,
                                                 float* __restrict__ ccp) {
    int j = blockIdx.x, t = threadIdx.x;
    __shared__ float red[4];
    __shared__ float bcast[2];
    const float* row = bbp + j * CC;
    float m = -1e30f;
    for (int c = t; c < CC; c += 256) m = fmaxf(m, row[c]);
#pragma unroll
    for (int o = 32; o > 0; o >>= 1) m = fmaxf(m, __shfl_down(m, o, 64));
    if ((t & 63) == 0) red[t >> 6] = m;
    __syncthreads();
    if (t == 0) bcast[0] = fmaxf(fmaxf(red[0], red[1]), fmaxf(red[2], red[3]));
    __syncthreads();
    float mm = bcast[0];
    float ssum = 0.f;
    for (int c = t; c < CC; c += 256) ssum += expf(row[c] - mm);
#pragma unroll
    for (int o = 32; o > 0; o >>= 1) ssum += __shfl_down(ssum, o, 64);
    if ((t & 63) == 0) red[t >> 6] = ssum;
    __syncthreads();
    if (t == 0) bcast[1] = red[0] + red[1] + red[2] + red[3];
    __syncthreads();
    float inv = 1.0f / bcast[1];
    for (int c = t; c < CC; c += 256) ccp[j * CC + c] = expf(row[c] - mm) * inv;
}

// ---------------------------------------------------------------------------
// Bmat[n=(j*16+s)][k8=c] (uint4 units; k=(c,u), u packed in uint4) =
//   bf16( cc[j,c] * W[c,j,s,u] ).  LDS tile transpose; coalesced both ways.
__global__ __launch_bounds__(256) void k_bmat(const void* __restrict__ W,
                                              const float* __restrict__ ccp,
                                              u16* __restrict__ Bm,
                                              const int* __restrict__ flag) {
    __shared__ uint4 lds[16][129];  // [ci][ni], padded
    int ct = blockIdx.x & 127, nt = blockIdx.x >> 7;
    int c0 = ct * 16, n0 = nt * 128;
    int t = threadIdx.x;
    int isbf = *flag;
    for (int q = t; q < 2048; q += 256) {
        int ci = q >> 7, ni = q & 127;
        int c = c0 + ci, n = n0 + ni;
        size_t widx = (size_t)c * 512 + n;
        float f[8];
        if (isbf) {
            uint4 p = ((const uint4*)W)[widx];
            f[0] = bflo(p.x); f[1] = bfhi(p.x); f[2] = bflo(p.y); f[3] = bfhi(p.y);
            f[4] = bflo(p.z); f[5] = bfhi(p.z); f[6] = bflo(p.w); f[7] = bfhi(p.w);
        } else {
            const float4* Wf = (const float4*)W;
            float4 lo = Wf[2 * widx], hi = Wf[2 * widx + 1];
            f[0] = lo.x; f[1] = lo.y; f[2] = lo.z; f[3] = lo.w;
            f[4] = hi.x; f[5] = hi.y; f[6] = hi.z; f[7] = hi.w;
        }
        float cw = ccp[(n >> 4) * CC + c];
        uint4 o;
        o.x = pack2(f[0] * cw, f[1] * cw);
        o.y = pack2(f[2] * cw, f[3] * cw);
        o.z = pack2(f[4] * cw, f[5] * cw);
        o.w = pack2(f[6] * cw, f[7] * cw);
        lds[ci][ni] = o;
    }
    __syncthreads();
    for (int q = t; q < 2048; q += 256) {
        int ni = q >> 4, ci = q & 15;
        ((uint4*)Bm)[(size_t)(n0 + ni) * 2048 + c0 + ci] = lds[ci][ni];
    }
}

// ---------------------------------------------------------------------------
// MFMA GEMM: spart[sl][b][n] = sum_{k in slice} xA[b][k] * Bmat[n][k].
// 128 blocks x 4 waves; wave = 2 m-tiles x 2 n-tiles (16x16x32 bf16),
// K-slice = 2048 (64 MFMA steps). Direct global b128 fragment loads (each
// load = 16 fully-used 64B lines; A/B are L2/L3-resident).
__global__ __launch_bounds__(256) void k_gemmA(const u16* __restrict__ xA,
                                               const u16* __restrict__ Bm,
                                               float* __restrict__ spart) {
    const bf16x8* A8 = (const bf16x8*)xA;
    const bf16x8* B8 = (const bf16x8*)Bm;
    int t = threadIdx.x;
    int w = t >> 6, lane = t & 63;
    int gw = blockIdx.x * 4 + w;       // [0,512)
    int sl = gw >> 6, rest = gw & 63;  // slice, then 4 mg x 16 ng
    int mg = rest & 3, ng = rest >> 2;
    int ln = lane & 15, quad = lane >> 4;
    int rowA0 = (mg * 32 + ln) * 2048;
    int rowA1 = rowA0 + 16 * 2048;
    int rowB0 = (ng * 32 + ln) * 2048;
    int rowB1 = rowB0 + 16 * 2048;
    int kk = sl * 256 + quad;
    f32x4 acc00 = {0.f, 0.f, 0.f, 0.f};
    f32x4 acc01 = acc00, acc10 = acc00, acc11 = acc00;
#pragma unroll 4
    for (int step = 0; step < 64; ++step) {
        bf16x8 a0 = A8[rowA0 + kk];
        bf16x8 a1 = A8[rowA1 + kk];
        bf16x8 b0 = B8[rowB0 + kk];
        bf16x8 b1 = B8[rowB1 + kk];
        kk += 4;
        acc00 = __builtin_amdgcn_mfma_f32_16x16x32_bf16(a0, b0, acc00, 0, 0, 0);
        acc01 = __builtin_amdgcn_mfma_f32_16x16x32_bf16(a0, b1, acc01, 0, 0, 0);
        acc10 = __builtin_amdgcn_mfma_f32_16x16x32_bf16(a1, b0, acc10, 0, 0, 0);
        acc11 = __builtin_amdgcn_mfma_f32_16x16x32_bf16(a1, b1, acc11, 0, 0, 0);
    }
    float* outp = spart + sl * (BB * JJ * SS);
    int b0r = mg * 32 + quad * 4;
    int n00 = ng * 32 + ln;
#pragma unroll
    for (int r = 0; r < 4; ++r) {
        int b = b0r + r;
        outp[b * 512 + n00] = acc00[r];
        outp[b * 512 + n00 + 16] = acc01[r];
        outp[(b + 16) * 512 + n00] = acc10[r];
        outp[(b + 16) * 512 + n00 + 16] = acc11[r];
    }
}

// ---------------------------------------------------------------------------
// Squash: sum the 8 K-slice partials, then norm over J (reference axis=1 of
// [B,J,S]). Output fp32.
__global__ __launch_bounds__(256) void k_squash(const float* __restrict__ spart,
                                                float* __restrict__ v_out,
                                                float* __restrict__ out,
                                                int write_out) {
    int idx = blockIdx.x * 256 + threadIdx.x;  // B*S = 2048
    if (idx >= BB * SS) return;
    int b = idx >> 4, si = idx & 15;
    float s[32];
    float msq = 0.f;
#pragma unroll
    for (int jj = 0; jj < 32; ++jj) {
        int o = b * 512 + jj * 16 + si;
        float v = 0.f;
#pragma unroll
        for (int sl = 0; sl < 8; ++sl) v += spart[sl * (BB * JJ * SS) + o];
        s[jj] = v;
        msq = fmaf(v, v, msq);
    }
    float scale = msq / ((1.f + msq) * sqrtf(fmaxf(msq, 1e-30f)));
#pragma unroll
    for (int jj = 0; jj < 32; ++jj) {
        float v = s[jj] * scale;
        v_out[b * 512 + jj * 16 + si] = v;
        if (write_out) out[b * 512 + jj * 16 + si] = v;
    }
}

// ---------------------------------------------------------------------------
// Pass B: bb[j][c] += (1/B) sum_{b,s} (sum_u W[c,j,s,u] x[b,u,c]) * v[b,j,s]
// Grid 4096 = 32 j * 128 c-chunks of 16. Thread = (bl<16 b-lanes, ci<16).
// W staged from fp32 (or raw bf16) directly.
__global__ __launch_bounds__(256) void k_passB(const u16* __restrict__ xA,
                                               const void* __restrict__ W,
                                               const float* __restrict__ v_in,
                                               float* __restrict__ bbp,
                                               const int* __restrict__ wflag) {
    __shared__ uint4 xlds[128 * 17];  // [b][ci] padded
    __shared__ uint4 wlds[16 * 17];   // [ci][sp] padded
    __shared__ float vlds[128 * 17];  // [b][sp] padded
    __shared__ float red[256];
    int j = blockIdx.x & 31;
    int c0 = (blockIdx.x >> 5) * 16;
    int t = threadIdx.x;
    int bl = t & 15, ci = t >> 4;
    const uint4* xA4 = (const uint4*)xA;
    for (int q = t; q < 2048; q += 256) {
        int b = q >> 4, cix = q & 15;
        xlds[b * 17 + cix] = xA4[(size_t)b * CC + c0 + cix];
    }
    {
        int ci2 = t >> 4, sp = t & 15;
        size_t widx = (size_t)(c0 + ci2) * 512 + j * 16 + sp;
        uint4 wp;
        if (*wflag) {
            wp = ((const uint4*)W)[widx];
        } else {
            const float4* Wf = (const float4*)W;
            float4 lo = Wf[2 * widx], hi = Wf[2 * widx + 1];
            wp.x = pack2(lo.x, lo.y);
            wp.y = pack2(lo.z, lo.w);
            wp.z = pack2(hi.x, hi.y);
            wp.w = pack2(hi.z, hi.w);
        }
        wlds[ci2 * 17 + sp] = wp;
    }
    for (int q = t; q < 2048; q += 256) {
        int b = q >> 4, sp = q & 15;
        vlds[b * 17 + sp] = v_in[b * 512 + j * 16 + sp];
    }
    __syncthreads();
    float xv[8][8];
#pragma unroll
    for (int k = 0; k < 8; ++k) {
        uint4 xp = xlds[(bl + k * 16) * 17 + ci];
        u32 a[4] = {xp.x, xp.y, xp.z, xp.w};
#pragma unroll
        for (int e = 0; e < 4; ++e) {
            xv[k][2 * e] = bflo(a[e]);
            xv[k][2 * e + 1] = bfhi(a[e]);
        }
    }
    float acc = 0.f;
#pragma unroll
    for (int sp = 0; sp < 16; ++sp) {
        uint4 wp = wlds[ci * 17 + sp];
        u32 a[4] = {wp.x, wp.y, wp.z, wp.w};
        float wv[8];
#pragma unroll
        for (int e = 0; e < 4; ++e) {
            wv[2 * e] = bflo(a[e]);
            wv[2 * e + 1] = bfhi(a[e]);
        }
#pragma unroll
        for (int k = 0; k < 8; ++k) {
            float d = 0.f;
#pragma unroll
            for (int u = 0; u < 8; ++u) d = fmaf(wv[u], xv[k][u], d);
            acc = fmaf(d, vlds[(bl + k * 16) * 17 + sp], acc);
        }
    }
    red[t] = acc;  // t == ci*16 + bl
    __syncthreads();
    if (t < 16) {
        float ssum = 0.f;
#pragma unroll
        for (int l = 0; l < 16; ++l) ssum += red[t * 16 + l];
        bbp[j * CC + c0 + t] += ssum * (1.0f / BB);
    }
}

// ---------------------------------------------------------------------------
extern "C" void kernel_launch(void* const* d_in, const int* in_sizes, int n_in,
                              void* d_out, int out_size, void* d_ws, size_t ws_size,
                              hipStream_t stream) {
    const void* x = d_in[0];
    const void* W = d_in[1];
    if (in_sizes[0] == CC * JJ * SS * UU) {  // robustness: order by size
        x = d_in[1];
        W = d_in[0];
    }
    float* out = (float*)d_out;  // fp32 output

    char* ws = (char*)d_ws;
    u16* Bm = (u16*)ws;                                   // 16 MiB
    u16* xA = (u16*)(ws + (16u << 20));                   // 4 MiB
    float* spart = (float*)(ws + (20u << 20));            // 2 MiB (8 slices)
    float* v_buf = (float*)(ws + (22u << 20));            // 256 KiB
    float* bbp = (float*)(ws + (22u << 20) + 262144);     // 256 KiB
    float* ccp = (float*)(ws + (22u << 20) + 2 * 262144); // 256 KiB
    int* flags = (int*)(ws + (22u << 20) + 3 * 262144);   // 2 ints

    k_detect<<<1, 256, 0, stream>>>((const u32*)x, flags + 0);
    k_detect<<<1, 256, 0, stream>>>((const u32*)W, flags + 1);
    k_build_xA<<<1024, 256, 0, stream>>>(x, xA, flags + 0);
    k_zero<<<256, 256, 0, stream>>>(bbp, CC * JJ);

    for (int it = 0; it < 3; ++it) {
        k_softmax<<<32, 256, 0, stream>>>(bbp, ccp);
        k_bmat<<<512, 256, 0, stream>>>(W, ccp, Bm, flags + 1);
        k_gemmA<<<128, 256, 0, stream>>>(xA, Bm, spart);
        k_squash<<<8, 256, 0, stream>>>(spart, v_buf, out, it == 2 ? 1 : 0);
        if (it < 2) k_passB<<<4096, 256, 0, stream>>>(xA, W, v_buf, bbp, flags + 1);
    }
}

// Round 8
// 366.742 us; speedup vs baseline: 1.1794x; 1.0063x over previous
//
#include <hip/hip_runtime.h>
#include <hip/hip_bf16.h>

// Problem: x [B,U,C] fp32, W [1,C,J,S,U] fp32, out [B,J,S,1] fp32.
// passA: bf16 MFMA GEMM s = xA · Bmat^T (Bmat = cc*W rebuilt per iter).
// passB: bf16 MFMA GEMM G_u = X_u^T·V fused with W∘G epilogue -> atomicAdd bb.
#define BB 128
#define UU 8
#define CC 2048
#define JJ 32
#define SS 16

typedef unsigned int u32;
typedef unsigned short u16;
typedef __attribute__((ext_vector_type(8))) short bf16x8;
typedef __attribute__((ext_vector_type(4))) float f32x4;

__device__ __forceinline__ float bflo(u32 p) { return __uint_as_float(p << 16); }
__device__ __forceinline__ float bfhi(u32 p) { return __uint_as_float(p & 0xffff0000u); }
__device__ __forceinline__ u32 f2b(float f) {  // RNE fp32->bf16 bits
    u32 bits = __float_as_uint(f);
    u32 r = bits + 0x7fffu + ((bits >> 16) & 1u);
    return r >> 16;
}
__device__ __forceinline__ u32 pack2(float a, float b) { return f2b(a) | (f2b(b) << 16); }

// ---------------------------------------------------------------------------
// Setup: block 0/1 = dtype detect for x/W (flag=1 -> bf16; proven fp32 in this
// harness, kept for robustness); blocks 2..17 zero bbp.
__global__ __launch_bounds__(256) void k_setup(const u32* __restrict__ x,
                                               const u32* __restrict__ W,
                                               int* __restrict__ flags,
                                               float* __restrict__ bbp) {
    int blk = blockIdx.x, t = threadIdx.x;
    if (blk < 2) {
        __shared__ int red[4];
        const u32* p = blk ? W : x;
        int cnt = 0;
        for (int i = t; i < 2048; i += 256) {
            u32 e = (p[i] >> 7) & 0xFF;
            cnt += (e >= 0x60 && e <= 0x8F) ? 1 : 0;
        }
#pragma unroll
        for (int o = 32; o > 0; o >>= 1) cnt += __shfl_down(cnt, o, 64);
        if ((t & 63) == 0) red[t >> 6] = cnt;
        __syncthreads();
        if (t == 0) flags[blk] = ((red[0] + red[1] + red[2] + red[3]) > 1228) ? 1 : 0;
    } else {
        int base = (blk - 2) * 4096 + t;
#pragma unroll
        for (int r = 0; r < 16; ++r) bbp[base + r * 256] = 0.f;
    }
}

// ---------------------------------------------------------------------------
// xA[b][c][u] packed bf16 from x[b][u][c]  (A-operand for gemmA: k=(c,u)).
__global__ __launch_bounds__(256) void k_build_xA(const void* __restrict__ x,
                                                  u16* __restrict__ xA,
                                                  const int* __restrict__ flag) {
    int b = blockIdx.x >> 3;
    int c = (blockIdx.x & 7) * 256 + threadIdx.x;
    uint4 p;
    if (*flag) {
        const u16* xh = (const u16*)x + (size_t)b * UU * CC;
        u16 v[8];
#pragma unroll
        for (int u = 0; u < 8; ++u) v[u] = xh[u * CC + c];
        p.x = (u32)v[0] | ((u32)v[1] << 16);
        p.y = (u32)v[2] | ((u32)v[3] << 16);
        p.z = (u32)v[4] | ((u32)v[5] << 16);
        p.w = (u32)v[6] | ((u32)v[7] << 16);
    } else {
        const float* xf = (const float*)x + (size_t)b * UU * CC;
        float v[8];
#pragma unroll
        for (int u = 0; u < 8; ++u) v[u] = xf[u * CC + c];
        p.x = pack2(v[0], v[1]);
        p.y = pack2(v[2], v[3]);
        p.z = pack2(v[4], v[5]);
        p.w = pack2(v[6], v[7]);
    }
    ((uint4*)xA)[(size_t)b * CC + c] = p;
}

// ---------------------------------------------------------------------------
// xB[u][c][b] packed bf16 from x[b][u][c]  (A-operand for gemmB: rows=c, k=b).
// Block = (u, 16-c chunk); LDS tile transpose.
__global__ __launch_bounds__(256) void k_build_xB(const void* __restrict__ x,
                                                  u16* __restrict__ xB,
                                                  const int* __restrict__ flag) {
    __shared__ float lds[16][129];
    int u = blockIdx.x >> 7;
    int c0 = (blockIdx.x & 127) * 16;
    int t = threadIdx.x;
    int b = t >> 1, h = t & 1;
    size_t row = ((size_t)b * UU + u) * CC + c0;
    if (*flag) {
        const u16* xh = (const u16*)x + row + h * 8;
#pragma unroll
        for (int e = 0; e < 8; ++e) lds[h * 8 + e][b] = bflo((u32)xh[e]);
    } else {
        const float4* x4 = (const float4*)((const float*)x + row);
        float4 lo = x4[h * 2], hi = x4[h * 2 + 1];
        lds[h * 8 + 0][b] = lo.x; lds[h * 8 + 1][b] = lo.y;
        lds[h * 8 + 2][b] = lo.z; lds[h * 8 + 3][b] = lo.w;
        lds[h * 8 + 4][b] = hi.x; lds[h * 8 + 5][b] = hi.y;
        lds[h * 8 + 6][b] = hi.z; lds[h * 8 + 7][b] = hi.w;
    }
    __syncthreads();
    int ci = t >> 4, k8 = t & 15;
    uint4 p;
    p.x = pack2(lds[ci][k8 * 8 + 0], lds[ci][k8 * 8 + 1]);
    p.y = pack2(lds[ci][k8 * 8 + 2], lds[ci][k8 * 8 + 3]);
    p.z = pack2(lds[ci][k8 * 8 + 4], lds[ci][k8 * 8 + 5]);
    p.w = pack2(lds[ci][k8 * 8 + 6], lds[ci][k8 * 8 + 7]);
    ((uint4*)xB)[((size_t)u * CC + c0 + ci) * 16 + k8] = p;
}

// ---------------------------------------------------------------------------
// Softmax over C for each j; bbp/ccp layout [j][c].
__global__ __launch_bounds__(256) void k_softmax(const float* __restrict__ bbp,
                                                 float* __restrict__ ccp) {
    int j = blockIdx.x, t = threadIdx.x;
    __shared__ float red[4];
    __shared__ float bcast[2];
    const float* row = bbp + j * CC;
    float m = -1e30f;
    for (int c = t; c < CC; c += 256) m = fmaxf(m, row[c]);
#pragma unroll
    for (int o = 32; o > 0; o >>= 1) m = fmaxf(m, __shfl_down(m, o, 64));
    if ((t & 63) == 0) red[t >> 6] = m;
    __syncthreads();
    if (t == 0) bcast[0] = fmaxf(fmaxf(red[0], red[1]), fmaxf(red[2], red[3]));
    __syncthreads();
    float mm = bcast[0];
    float ssum = 0.f;
    for (int c = t; c < CC; c += 256) ssum += expf(row[c] - mm);
#pragma unroll
    for (int o = 32; o > 0; o >>= 1) ssum += __shfl_down(ssum, o, 64);
    if ((t & 63) == 0) red[t >> 6] = ssum;
    __syncthreads();
    if (t == 0) bcast[1] = red[0] + red[1] + red[2] + red[3];
    __syncthreads();
    float inv = 1.0f / bcast[1];
    for (int c = t; c < CC; c += 256) ccp[j * CC + c] = expf(row[c] - mm) * inv;
}

// ---------------------------------------------------------------------------
// Bmat[n=(j*16+s)][k8=c] = bf16( cc[j,c] * W[c,j,s,u] ), u packed in uint4.
__global__ __launch_bounds__(256) void k_bmat(const void* __restrict__ W,
                                              const float* __restrict__ ccp,
                                              u16* __restrict__ Bm,
                                              const int* __restrict__ flag) {
    __shared__ uint4 lds[16][129];
    int ct = blockIdx.x & 127, nt = blockIdx.x >> 7;
    int c0 = ct * 16, n0 = nt * 128;
    int t = threadIdx.x;
    int isbf = *flag;
    for (int q = t; q < 2048; q += 256) {
        int ci = q >> 7, ni = q & 127;
        int c = c0 + ci, n = n0 + ni;
        size_t widx = (size_t)c * 512 + n;
        float f[8];
        if (isbf) {
            uint4 p = ((const uint4*)W)[widx];
            f[0] = bflo(p.x); f[1] = bfhi(p.x); f[2] = bflo(p.y); f[3] = bfhi(p.y);
            f[4] = bflo(p.z); f[5] = bfhi(p.z); f[6] = bflo(p.w); f[7] = bfhi(p.w);
        } else {
            const float4* Wf = (const float4*)W;
            float4 lo = Wf[2 * widx], hi = Wf[2 * widx + 1];
            f[0] = lo.x; f[1] = lo.y; f[2] = lo.z; f[3] = lo.w;
            f[4] = hi.x; f[5] = hi.y; f[6] = hi.z; f[7] = hi.w;
        }
        float cw = ccp[(n >> 4) * CC + c];
        uint4 o;
        o.x = pack2(f[0] * cw, f[1] * cw);
        o.y = pack2(f[2] * cw, f[3] * cw);
        o.z = pack2(f[4] * cw, f[5] * cw);
        o.w = pack2(f[6] * cw, f[7] * cw);
        lds[ci][ni] = o;
    }
    __syncthreads();
    for (int q = t; q < 2048; q += 256) {
        int ni = q >> 4, ci = q & 15;
        ((uint4*)Bm)[(size_t)(n0 + ni) * 2048 + c0 + ci] = lds[ci][ni];
    }
}

// ---------------------------------------------------------------------------
// gemmA: spart[sl][b][n] = sum_{k in slice} xA[b][k] * Bm[n][k].
// 256 blocks x 2 waves (all CUs active); wave = 2 m x 2 n tiles (16x16x32).
__global__ __launch_bounds__(128) void k_gemmA(const u16* __restrict__ xA,
                                               const u16* __restrict__ Bm,
                                               float* __restrict__ spart) {
    const bf16x8* A8 = (const bf16x8*)xA;
    const bf16x8* B8 = (const bf16x8*)Bm;
    int t = threadIdx.x;
    int w = t >> 6, lane = t & 63;
    int gw = blockIdx.x * 2 + w;       // [0,512)
    int sl = gw >> 6, rest = gw & 63;  // slice, then 4 mg x 16 ng
    int mg = rest & 3, ng = rest >> 2;
    int ln = lane & 15, quad = lane >> 4;
    int rowA0 = (mg * 32 + ln) * 2048;
    int rowA1 = rowA0 + 16 * 2048;
    int rowB0 = (ng * 32 + ln) * 2048;
    int rowB1 = rowB0 + 16 * 2048;
    int kk = sl * 256 + quad;
    f32x4 acc00 = {0.f, 0.f, 0.f, 0.f};
    f32x4 acc01 = acc00, acc10 = acc00, acc11 = acc00;
#pragma unroll 4
    for (int step = 0; step < 64; ++step) {
        bf16x8 a0 = A8[rowA0 + kk];
        bf16x8 a1 = A8[rowA1 + kk];
        bf16x8 b0 = B8[rowB0 + kk];
        bf16x8 b1 = B8[rowB1 + kk];
        kk += 4;
        acc00 = __builtin_amdgcn_mfma_f32_16x16x32_bf16(a0, b0, acc00, 0, 0, 0);
        acc01 = __builtin_amdgcn_mfma_f32_16x16x32_bf16(a0, b1, acc01, 0, 0, 0);
        acc10 = __builtin_amdgcn_mfma_f32_16x16x32_bf16(a1, b0, acc10, 0, 0, 0);
        acc11 = __builtin_amdgcn_mfma_f32_16x16x32_bf16(a1, b1, acc11, 0, 0, 0);
    }
    float* outp = spart + sl * (BB * JJ * SS);
    int b0r = mg * 32 + quad * 4;
    int n00 = ng * 32 + ln;
#pragma unroll
    for (int r = 0; r < 4; ++r) {
        int b = b0r + r;
        outp[b * 512 + n00] = acc00[r];
        outp[b * 512 + n00 + 16] = acc01[r];
        outp[(b + 16) * 512 + n00] = acc10[r];
        outp[(b + 16) * 512 + n00 + 16] = acc11[r];
    }
}

// ---------------------------------------------------------------------------
// Squash: sum 8 K-slice partials, norm over J; emit fp32 out (last iter) and
// vB[n][b] bf16 (B-operand for gemmB).
__global__ __launch_bounds__(256) void k_squash(const float* __restrict__ spart,
                                                u16* __restrict__ vB,
                                                float* __restrict__ out,
                                                int write_out) {
    int idx = blockIdx.x * 256 + threadIdx.x;  // B*S = 2048
    if (idx >= BB * SS) return;
    int b = idx >> 4, si = idx & 15;
    float s[32];
    float msq = 0.f;
#pragma unroll
    for (int jj = 0; jj < 32; ++jj) {
        int o = b * 512 + jj * 16 + si;
        float v = 0.f;
#pragma unroll
        for (int sl = 0; sl < 8; ++sl) v += spart[sl * (BB * JJ * SS) + o];
        s[jj] = v;
        msq = fmaf(v, v, msq);
    }
    float scale = msq / ((1.f + msq) * sqrtf(fmaxf(msq, 1e-30f)));
#pragma unroll
    for (int jj = 0; jj < 32; ++jj) {
        float v = s[jj] * scale;
        vB[(jj * 16 + si) * BB + b] = (u16)f2b(v);
        if (write_out) out[b * 512 + jj * 16 + si] = v;
    }
}

// ---------------------------------------------------------------------------
// gemmB: G[c,(j,s)] = sum_b xB[u][c][b] * vB[(j,s)][b]; epilogue folds
// W[c,j,s,u], xor-reduces over s-lanes, atomicAdds (1/B)*sum into bbp[j][c].
// 256 blocks x 4 waves; wave = (u, 16-c tile) x 32 j-tiles.
__global__ __launch_bounds__(256) void k_gemmB(const u16* __restrict__ xB,
                                               const void* __restrict__ W,
                                               const u16* __restrict__ vB,
                                               float* __restrict__ bbp,
                                               const int* __restrict__ wflag) {
    const bf16x8* A8 = (const bf16x8*)xB;
    const bf16x8* B8 = (const bf16x8*)vB;
    int t = threadIdx.x;
    int w = t >> 6, lane = t & 63;
    int gw = blockIdx.x * 4 + w;  // [0,1024)
    int u = gw >> 7, c0 = (gw & 127) * 16;
    int ln = lane & 15, quad = lane >> 4;
    int isbf = *wflag;
    bf16x8 af[4];
    int arow = (u * CC + c0 + ln) * 16;
#pragma unroll
    for (int s = 0; s < 4; ++s) af[s] = A8[arow + quad + 4 * s];
    for (int nt = 0; nt < 32; ++nt) {
        f32x4 acc = {0.f, 0.f, 0.f, 0.f};
        int brow = (nt * 16 + ln) * 16;
#pragma unroll
        for (int s = 0; s < 4; ++s) {
            bf16x8 bfr = B8[brow + quad + 4 * s];
            acc = __builtin_amdgcn_mfma_f32_16x16x32_bf16(af[s], bfr, acc, 0, 0, 0);
        }
        // lane holds G[c = c0+quad*4+r][(j=nt, s=ln)]
        float val[4];
#pragma unroll
        for (int r = 0; r < 4; ++r) {
            int c = c0 + quad * 4 + r;
            size_t widx = ((size_t)c * 512 + nt * 16 + ln) * 8 + u;
            float wv = isbf ? bflo((u32)((const u16*)W)[widx])
                            : ((const float*)W)[widx];
            val[r] = acc[r] * wv;
        }
#pragma unroll
        for (int m = 1; m <= 8; m <<= 1) {
#pragma unroll
            for (int r = 0; r < 4; ++r) val[r] += __shfl_xor(val[r], m, 64);
        }
        if (ln == 0) {
#pragma unroll
            for (int r = 0; r < 4; ++r)
                atomicAdd(&bbp[nt * CC + c0 + quad * 4 + r], val[r] * (1.0f / BB));
        }
    }
}

// ---------------------------------------------------------------------------
extern "C" void kernel_launch(void* const* d_in, const int* in_sizes, int n_in,
                              void* d_out, int out_size, void* d_ws, size_t ws_size,
                              hipStream_t stream) {
    const void* x = d_in[0];
    const void* W = d_in[1];
    if (in_sizes[0] == CC * JJ * SS * UU) {  // robustness: order by size
        x = d_in[1];
        W = d_in[0];
    }
    float* out = (float*)d_out;  // fp32 output

    char* ws = (char*)d_ws;
    u16* Bm = (u16*)ws;                                    // 16 MiB
    u16* xA = (u16*)(ws + (16u << 20));                    // 4 MiB
    u16* xB = (u16*)(ws + (20u << 20));                    // 4 MiB
    float* spart = (float*)(ws + (24u << 20));             // 2 MiB (8 slices)
    u16* vB = (u16*)(ws + (26u << 20));                    // 128 KiB
    float* bbp = (float*)(ws + (26u << 20) + 131072);      // 256 KiB
    float* ccp = (float*)(ws + (26u << 20) + 131072 + 262144);
    int* flags = (int*)(ws + (26u << 20) + 131072 + 2 * 262144);

    k_setup<<<18, 256, 0, stream>>>((const u32*)x, (const u32*)W, flags, bbp);
    k_build_xA<<<1024, 256, 0, stream>>>(x, xA, flags + 0);
    k_build_xB<<<1024, 256, 0, stream>>>(x, xB, flags + 0);

    for (int it = 0; it < 3; ++it) {
        k_softmax<<<32, 256, 0, stream>>>(bbp, ccp);
        k_bmat<<<512, 256, 0, stream>>>(W, ccp, Bm, flags + 1);
        k_gemmA<<<256, 128, 0, stream>>>(xA, Bm, spart);
        k_squash<<<8, 256, 0, stream>>>(spart, vB, out, it == 2 ? 1 : 0);
        if (it < 2) k_gemmB<<<256, 256, 0, stream>>>(xB, W, vB, bbp, flags + 1);
    }
}

// Round 9
// 284.978 us; speedup vs baseline: 1.5178x; 1.2869x over previous
//
#include <hip/hip_runtime.h>
#include <hip/hip_bf16.h>

// Problem: x [B,U,C] fp32, W [1,C,J,S,U] fp32, out [B,J,S,1] fp32.
// passA: bf16 MFMA GEMM s = xA · Bmat^T (Bmat = cc*W rebuilt per iter).
// passB: bf16 MFMA GEMM G[u][n][c] = sum_b vB[n][b] xB[u][c][b] (G aliases Bm),
//        then coalesced contraction bb[j][c] += (1/B) sum_{s,u} W*G.
#define BB 128
#define UU 8
#define CC 2048
#define JJ 32
#define SS 16

typedef unsigned int u32;
typedef unsigned short u16;
typedef __attribute__((ext_vector_type(8))) short bf16x8;
typedef __attribute__((ext_vector_type(4))) float f32x4;

__device__ __forceinline__ float bflo(u32 p) { return __uint_as_float(p << 16); }
__device__ __forceinline__ float bfhi(u32 p) { return __uint_as_float(p & 0xffff0000u); }
__device__ __forceinline__ u32 f2b(float f) {  // RNE fp32->bf16 bits
    u32 bits = __float_as_uint(f);
    u32 r = bits + 0x7fffu + ((bits >> 16) & 1u);
    return r >> 16;
}
__device__ __forceinline__ u32 pack2(float a, float b) { return f2b(a) | (f2b(b) << 16); }

// ---------------------------------------------------------------------------
// Setup: blocks 0/1 detect dtype of x/W (flag=1 -> bf16; fp32 in this
// harness, kept for robustness); blocks 2..17 zero bbp.
__global__ __launch_bounds__(256) void k_setup(const u32* __restrict__ x,
                                               const u32* __restrict__ W,
                                               int* __restrict__ flags,
                                               float* __restrict__ bbp) {
    int blk = blockIdx.x, t = threadIdx.x;
    if (blk < 2) {
        __shared__ int red[4];
        const u32* p = blk ? W : x;
        int cnt = 0;
        for (int i = t; i < 2048; i += 256) {
            u32 e = (p[i] >> 7) & 0xFF;
            cnt += (e >= 0x60 && e <= 0x8F) ? 1 : 0;
        }
#pragma unroll
        for (int o = 32; o > 0; o >>= 1) cnt += __shfl_down(cnt, o, 64);
        if ((t & 63) == 0) red[t >> 6] = cnt;
        __syncthreads();
        if (t == 0) flags[blk] = ((red[0] + red[1] + red[2] + red[3]) > 1228) ? 1 : 0;
    } else {
        int base = (blk - 2) * 4096 + t;
#pragma unroll
        for (int r = 0; r < 16; ++r) bbp[base + r * 256] = 0.f;
    }
}

// ---------------------------------------------------------------------------
// xA[b][c][u] packed bf16 from x[b][u][c]  (A-operand for gemmA: k=(c,u)).
__global__ __launch_bounds__(256) void k_build_xA(const void* __restrict__ x,
                                                  u16* __restrict__ xA,
                                                  const int* __restrict__ flag) {
    int b = blockIdx.x >> 3;
    int c = (blockIdx.x & 7) * 256 + threadIdx.x;
    uint4 p;
    if (*flag) {
        const u16* xh = (const u16*)x + (size_t)b * UU * CC;
        u16 v[8];
#pragma unroll
        for (int u = 0; u < 8; ++u) v[u] = xh[u * CC + c];
        p.x = (u32)v[0] | ((u32)v[1] << 16);
        p.y = (u32)v[2] | ((u32)v[3] << 16);
        p.z = (u32)v[4] | ((u32)v[5] << 16);
        p.w = (u32)v[6] | ((u32)v[7] << 16);
    } else {
        const float* xf = (const float*)x + (size_t)b * UU * CC;
        float v[8];
#pragma unroll
        for (int u = 0; u < 8; ++u) v[u] = xf[u * CC + c];
        p.x = pack2(v[0], v[1]);
        p.y = pack2(v[2], v[3]);
        p.z = pack2(v[4], v[5]);
        p.w = pack2(v[6], v[7]);
    }
    ((uint4*)xA)[(size_t)b * CC + c] = p;
}

// ---------------------------------------------------------------------------
// xB[u][c][b] packed bf16 from x[b][u][c]  (B-operand for gemmB1: rows=c, k=b).
__global__ __launch_bounds__(256) void k_build_xB(const void* __restrict__ x,
                                                  u16* __restrict__ xB,
                                                  const int* __restrict__ flag) {
    __shared__ float lds[16][129];
    int u = blockIdx.x >> 7;
    int c0 = (blockIdx.x & 127) * 16;
    int t = threadIdx.x;
    int b = t >> 1, h = t & 1;
    size_t row = ((size_t)b * UU + u) * CC + c0;
    if (*flag) {
        const u16* xh = (const u16*)x + row + h * 8;
#pragma unroll
        for (int e = 0; e < 8; ++e) lds[h * 8 + e][b] = bflo((u32)xh[e]);
    } else {
        const float4* x4 = (const float4*)((const float*)x + row);
        float4 lo = x4[h * 2], hi = x4[h * 2 + 1];
        lds[h * 8 + 0][b] = lo.x; lds[h * 8 + 1][b] = lo.y;
        lds[h * 8 + 2][b] = lo.z; lds[h * 8 + 3][b] = lo.w;
        lds[h * 8 + 4][b] = hi.x; lds[h * 8 + 5][b] = hi.y;
        lds[h * 8 + 6][b] = hi.z; lds[h * 8 + 7][b] = hi.w;
    }
    __syncthreads();
    int ci = t >> 4, k8 = t & 15;
    uint4 p;
    p.x = pack2(lds[ci][k8 * 8 + 0], lds[ci][k8 * 8 + 1]);
    p.y = pack2(lds[ci][k8 * 8 + 2], lds[ci][k8 * 8 + 3]);
    p.z = pack2(lds[ci][k8 * 8 + 4], lds[ci][k8 * 8 + 5]);
    p.w = pack2(lds[ci][k8 * 8 + 6], lds[ci][k8 * 8 + 7]);
    ((uint4*)xB)[((size_t)u * CC + c0 + ci) * 16 + k8] = p;
}

// ---------------------------------------------------------------------------
// Softmax over C for each j; bbp/ccp layout [j][c].
__global__ __launch_bounds__(256) void k_softmax(const float* __restrict__ bbp,
                                                 float* __restrict__ ccp) {
    int j = blockIdx.x, t = threadIdx.x;
    __shared__ float red[4];
    __shared__ float bcast[2];
    const float* row = bbp + j * CC;
    float m = -1e30f;
    for (int c = t; c < CC; c += 256) m = fmaxf(m, row[c]);
#pragma unroll
    for (int o = 32; o > 0; o >>= 1) m = fmaxf(m, __shfl_down(m, o, 64));
    if ((t & 63) == 0) red[t >> 6] = m;
    __syncthreads();
    if (t == 0) bcast[0] = fmaxf(fmaxf(red[0], red[1]), fmaxf(red[2], red[3]));
    __syncthreads();
    float mm = bcast[0];
    float ssum = 0.f;
    for (int c = t; c < CC; c += 256) ssum += expf(row[c] - mm);
#pragma unroll
    for (int o = 32; o > 0; o >>= 1) ssum += __shfl_down(ssum, o, 64);
    if ((t & 63) == 0) red[t >> 6] = ssum;
    __syncthreads();
    if (t == 0) bcast[1] = red[0] + red[1] + red[2] + red[3];
    __syncthreads();
    float inv = 1.0f / bcast[1];
    for (int c = t; c < CC; c += 256) ccp[j * CC + c] = expf(row[c] - mm) * inv;
}

// ---------------------------------------------------------------------------
// Bmat[n=(j*16+s)][k8=c] = bf16( cc[j,c] * W[c,j,s,u] ), u packed in uint4.
__global__ __launch_bounds__(256) void k_bmat(const void* __restrict__ W,
                                              const float* __restrict__ ccp,
                                              u16* __restrict__ Bm,
                                              const int* __restrict__ flag) {
    __shared__ uint4 lds[16][129];
    int ct = blockIdx.x & 127, nt = blockIdx.x >> 7;
    int c0 = ct * 16, n0 = nt * 128;
    int t = threadIdx.x;
    int isbf = *flag;
    for (int q = t; q < 2048; q += 256) {
        int ci = q >> 7, ni = q & 127;
        int c = c0 + ci, n = n0 + ni;
        size_t widx = (size_t)c * 512 + n;
        float f[8];
        if (isbf) {
            uint4 p = ((const uint4*)W)[widx];
            f[0] = bflo(p.x); f[1] = bfhi(p.x); f[2] = bflo(p.y); f[3] = bfhi(p.y);
            f[4] = bflo(p.z); f[5] = bfhi(p.z); f[6] = bflo(p.w); f[7] = bfhi(p.w);
        } else {
            const float4* Wf = (const float4*)W;
            float4 lo = Wf[2 * widx], hi = Wf[2 * widx + 1];
            f[0] = lo.x; f[1] = lo.y; f[2] = lo.z; f[3] = lo.w;
            f[4] = hi.x; f[5] = hi.y; f[6] = hi.z; f[7] = hi.w;
        }
        float cw = ccp[(n >> 4) * CC + c];
        uint4 o;
        o.x = pack2(f[0] * cw, f[1] * cw);
        o.y = pack2(f[2] * cw, f[3] * cw);
        o.z = pack2(f[4] * cw, f[5] * cw);
        o.w = pack2(f[6] * cw, f[7] * cw);
        lds[ci][ni] = o;
    }
    __syncthreads();
    for (int q = t; q < 2048; q += 256) {
        int ni = q >> 4, ci = q & 15;
        ((uint4*)Bm)[(size_t)(n0 + ni) * 2048 + c0 + ci] = lds[ci][ni];
    }
}

// ---------------------------------------------------------------------------
// gemmA: spart[sl][b][n] = sum_{k in slice} xA[b][k] * Bm[n][k].
// 16 K-slices, 256 blocks x 4 waves (1024 waves); wave = 2m x 2n tiles.
__global__ __launch_bounds__(256) void k_gemmA(const u16* __restrict__ xA,
                                               const u16* __restrict__ Bm,
                                               float* __restrict__ spart) {
    const bf16x8* A8 = (const bf16x8*)xA;
    const bf16x8* B8 = (const bf16x8*)Bm;
    int t = threadIdx.x;
    int w = t >> 6, lane = t & 63;
    int gw = blockIdx.x * 4 + w;       // [0,1024)
    int sl = gw >> 6, rest = gw & 63;  // slice, then 4 mg x 16 ng
    int mg = rest & 3, ng = rest >> 2;
    int ln = lane & 15, quad = lane >> 4;
    int rowA0 = (mg * 32 + ln) * 2048;
    int rowA1 = rowA0 + 16 * 2048;
    int rowB0 = (ng * 32 + ln) * 2048;
    int rowB1 = rowB0 + 16 * 2048;
    int kk = sl * 128 + quad;
    f32x4 acc00 = {0.f, 0.f, 0.f, 0.f};
    f32x4 acc01 = acc00, acc10 = acc00, acc11 = acc00;
#pragma unroll 4
    for (int step = 0; step < 32; ++step) {
        bf16x8 a0 = A8[rowA0 + kk];
        bf16x8 a1 = A8[rowA1 + kk];
        bf16x8 b0 = B8[rowB0 + kk];
        bf16x8 b1 = B8[rowB1 + kk];
        kk += 4;
        acc00 = __builtin_amdgcn_mfma_f32_16x16x32_bf16(a0, b0, acc00, 0, 0, 0);
        acc01 = __builtin_amdgcn_mfma_f32_16x16x32_bf16(a0, b1, acc01, 0, 0, 0);
        acc10 = __builtin_amdgcn_mfma_f32_16x16x32_bf16(a1, b0, acc10, 0, 0, 0);
        acc11 = __builtin_amdgcn_mfma_f32_16x16x32_bf16(a1, b1, acc11, 0, 0, 0);
    }
    float* outp = spart + sl * (BB * JJ * SS);
    int b0r = mg * 32 + quad * 4;
    int n00 = ng * 32 + ln;
#pragma unroll
    for (int r = 0; r < 4; ++r) {
        int b = b0r + r;
        outp[b * 512 + n00] = acc00[r];
        outp[b * 512 + n00 + 16] = acc01[r];
        outp[(b + 16) * 512 + n00] = acc10[r];
        outp[(b + 16) * 512 + n00 + 16] = acc11[r];
    }
}

// ---------------------------------------------------------------------------
// Reduce the 16 K-slice partials: s_buf[i] = sum_sl spart[sl][i].
__global__ __launch_bounds__(256) void k_reduce(const float* __restrict__ spart,
                                                float* __restrict__ s_buf) {
    int idx = blockIdx.x * 256 + threadIdx.x;  // 65536
    float v = 0.f;
#pragma unroll
    for (int sl = 0; sl < 16; ++sl) v += spart[sl * (BB * JJ * SS) + idx];
    s_buf[idx] = v;
}

// ---------------------------------------------------------------------------
// Squash: norm over J (reference axis=1 of [B,J,S]); emit fp32 out (last
// iter) and vB[n][b] bf16 (A-operand for gemmB1).
__global__ __launch_bounds__(256) void k_squash(const float* __restrict__ s_buf,
                                                u16* __restrict__ vB,
                                                float* __restrict__ out,
                                                int write_out) {
    int idx = blockIdx.x * 256 + threadIdx.x;  // B*S = 2048
    if (idx >= BB * SS) return;
    int b = idx >> 4, si = idx & 15;
    float s[32];
    float msq = 0.f;
#pragma unroll
    for (int jj = 0; jj < 32; ++jj) {
        float v = s_buf[b * 512 + jj * 16 + si];
        s[jj] = v;
        msq = fmaf(v, v, msq);
    }
    float scale = msq / ((1.f + msq) * sqrtf(fmaxf(msq, 1e-30f)));
#pragma unroll
    for (int jj = 0; jj < 32; ++jj) {
        float v = s[jj] * scale;
        vB[(jj * 16 + si) * BB + b] = (u16)f2b(v);
        if (write_out) out[b * 512 + jj * 16 + si] = v;
    }
}

// ---------------------------------------------------------------------------
// gemmB1: G[u][n][c] = sum_b vB[n][b] * xB[u][c][b]  (bf16 out; aliases Bm).
// 2048 blocks x 4 waves = 8192 waves; wave = (u, 32n x 32c tile), K=128.
__global__ __launch_bounds__(256) void k_gemmB1(const u16* __restrict__ vB,
                                                const u16* __restrict__ xB,
                                                u16* __restrict__ G) {
    const bf16x8* A8 = (const bf16x8*)vB;
    const bf16x8* B8 = (const bf16x8*)xB;
    int t = threadIdx.x;
    int w = t >> 6, lane = t & 63;
    int gw = blockIdx.x * 4 + w;  // [0,8192)
    int u = gw >> 10, rest = gw & 1023;
    int n0 = (rest & 15) * 32, c0 = (rest >> 4) * 32;
    int ln = lane & 15, quad = lane >> 4;
    bf16x8 av[2][4], bx[2][4];
#pragma unroll
    for (int mt = 0; mt < 2; ++mt)
#pragma unroll
        for (int st = 0; st < 4; ++st)
            av[mt][st] = A8[(n0 + mt * 16 + ln) * 16 + quad + 4 * st];
#pragma unroll
    for (int ct = 0; ct < 2; ++ct)
#pragma unroll
        for (int st = 0; st < 4; ++st)
            bx[ct][st] = B8[((size_t)u * CC + c0 + ct * 16 + ln) * 16 + quad + 4 * st];
    f32x4 acc[2][2];
    acc[0][0] = {0.f, 0.f, 0.f, 0.f};
    acc[0][1] = acc[0][0]; acc[1][0] = acc[0][0]; acc[1][1] = acc[0][0];
#pragma unroll
    for (int st = 0; st < 4; ++st)
#pragma unroll
        for (int mt = 0; mt < 2; ++mt)
#pragma unroll
            for (int ct = 0; ct < 2; ++ct)
                acc[mt][ct] = __builtin_amdgcn_mfma_f32_16x16x32_bf16(
                    av[mt][st], bx[ct][st], acc[mt][ct], 0, 0, 0);
#pragma unroll
    for (int mt = 0; mt < 2; ++mt)
#pragma unroll
        for (int ct = 0; ct < 2; ++ct)
#pragma unroll
            for (int r = 0; r < 4; ++r) {
                int n = n0 + mt * 16 + quad * 4 + r;
                int c = c0 + ct * 16 + ln;
                G[((size_t)u * 512 + n) * 2048 + c] = (u16)f2b(acc[mt][ct][r]);
            }
}

// ---------------------------------------------------------------------------
// bbsum: bb[j][c] += (1/B) sum_{s,u} W[c][j*16+s][u] * G[u][j*16+s][c].
// Grid 512 = 32 j x 16 c-chunks(128). W staged to LDS coalesced (bf16-packed
// pairs along u); G read coalesced (u32 = 2 consecutive c).
__global__ __launch_bounds__(256) void k_bbsum(const void* __restrict__ W,
                                               const u16* __restrict__ G,
                                               float* __restrict__ bbp,
                                               const int* __restrict__ wflag) {
    __shared__ u32 Wlds[128][65];  // [ci][s*4 + u/2], pad 65
    __shared__ float red[4][128];
    int j = blockIdx.x & 31;
    int c0 = (blockIdx.x >> 5) * 128;
    int t = threadIdx.x;
    int isbf = *wflag;
#pragma unroll
    for (int it = 0; it < 16; ++it) {
        int q = t + it * 256;
        int ci = q >> 5, f4 = q & 31;
        size_t fbase = ((size_t)(c0 + ci) * 512 + j * 16) * 8 + f4 * 4;
        u32 p0, p1;
        if (isbf) {
            const u32* W32 = (const u32*)W;
            p0 = W32[fbase >> 1];
            p1 = W32[(fbase >> 1) + 1];
        } else {
            float4 f = ((const float4*)W)[fbase >> 2];
            p0 = pack2(f.x, f.y);
            p1 = pack2(f.z, f.w);
        }
        Wlds[ci][f4 * 2] = p0;
        Wlds[ci][f4 * 2 + 1] = p1;
    }
    __syncthreads();
    int w = t >> 6, cp = t & 63;  // wave w owns u in {2w,2w+1}; thread 2 c's
    const u32* G32 = (const u32*)G;
    float acc0 = 0.f, acc1 = 0.f;
    int u0 = 2 * w;
#pragma unroll
    for (int s = 0; s < 16; ++s) {
        u32 wl = Wlds[2 * cp][s * 4 + w];      // (c even; u0, u0+1)
        u32 wh = Wlds[2 * cp + 1][s * 4 + w];  // (c odd;  u0, u0+1)
        int n = j * 16 + s;
        u32 g0 = G32[((size_t)u0 * 512 + n) * 1024 + (c0 >> 1) + cp];
        u32 g1 = G32[((size_t)(u0 + 1) * 512 + n) * 1024 + (c0 >> 1) + cp];
        acc0 = fmaf(bflo(wl), bflo(g0), acc0);
        acc0 = fmaf(bfhi(wl), bflo(g1), acc0);
        acc1 = fmaf(bflo(wh), bfhi(g0), acc1);
        acc1 = fmaf(bfhi(wh), bfhi(g1), acc1);
    }
    red[w][2 * cp] = acc0;
    red[w][2 * cp + 1] = acc1;
    __syncthreads();
    if (t < 128) {
        float sum = red[0][t] + red[1][t] + red[2][t] + red[3][t];
        bbp[j * CC + c0 + t] += sum * (1.0f / BB);
    }
}

// ---------------------------------------------------------------------------
extern "C" void kernel_launch(void* const* d_in, const int* in_sizes, int n_in,
                              void* d_out, int out_size, void* d_ws, size_t ws_size,
                              hipStream_t stream) {
    const void* x = d_in[0];
    const void* W = d_in[1];
    if (in_sizes[0] == CC * JJ * SS * UU) {  // robustness: order by size
        x = d_in[1];
        W = d_in[0];
    }
    float* out = (float*)d_out;  // fp32 output

    char* ws = (char*)d_ws;
    u16* Bm = (u16*)ws;                       // 16 MiB (aliased by G)
    u16* G = (u16*)ws;                        // 16 MiB (dead Bm between uses)
    u16* xA = (u16*)(ws + (16u << 20));       // 4 MiB
    u16* xB = (u16*)(ws + (20u << 20));       // 4 MiB
    float* spart = (float*)(ws + (24u << 20));  // 4 MiB (16 slices)
    size_t b28 = (size_t)28u << 20;
    float* s_buf = (float*)(ws + b28);              // 256 KiB
    u16* vB = (u16*)(ws + b28 + 262144);            // 128 KiB
    float* bbp = (float*)(ws + b28 + 393216);       // 256 KiB
    float* ccp = (float*)(ws + b28 + 655360);       // 256 KiB
    int* flags = (int*)(ws + b28 + 917504);

    k_setup<<<18, 256, 0, stream>>>((const u32*)x, (const u32*)W, flags, bbp);
    k_build_xA<<<1024, 256, 0, stream>>>(x, xA, flags + 0);
    k_build_xB<<<1024, 256, 0, stream>>>(x, xB, flags + 0);

    for (int it = 0; it < 3; ++it) {
        k_softmax<<<32, 256, 0, stream>>>(bbp, ccp);
        k_bmat<<<512, 256, 0, stream>>>(W, ccp, Bm, flags + 1);
        k_gemmA<<<256, 256, 0, stream>>>(xA, Bm, spart);
        k_reduce<<<256, 256, 0, stream>>>(spart, s_buf);
        k_squash<<<8, 256, 0, stream>>>(s_buf, vB, out, it == 2 ? 1 : 0);
        if (it < 2) {
            k_gemmB1<<<2048, 256, 0, stream>>>(vB, xB, G);
            k_bbsum<<<512, 256, 0, stream>>>(W, G, bbp, flags + 1);
        }
    }
}

// Round 10
// 244.151 us; speedup vs baseline: 1.7717x; 1.1672x over previous
//
#include <hip/hip_runtime.h>
#include <hip/hip_bf16.h>

// Problem: x [B,U,C] fp32, W [1,C,J,S,U] fp32, out [B,J,S,1] fp32.
// passA: bf16 MFMA GEMM s = xA · Bm^T, Bm = cc*Wn; Wn (bf16, GEMM layout)
//        built once. it0 uses Wn directly (cc uniform 1/2048 -> scalar in rsq).
// passB: bf16 MFMA GEMM G[u][n][c] = sum_b vB[n][b] xB[u][c][b] (G aliases Bm),
//        then coalesced contraction bb[j][c] += (1/B) sum_{s,u} W*G.
#define BB 128
#define UU 8
#define CC 2048
#define JJ 32
#define SS 16

typedef unsigned int u32;
typedef unsigned short u16;
typedef __attribute__((ext_vector_type(8))) short bf16x8;
typedef __attribute__((ext_vector_type(4))) float f32x4;

__device__ __forceinline__ float bflo(u32 p) { return __uint_as_float(p << 16); }
__device__ __forceinline__ float bfhi(u32 p) { return __uint_as_float(p & 0xffff0000u); }
__device__ __forceinline__ u32 f2b(float f) {  // RNE fp32->bf16 bits
    u32 bits = __float_as_uint(f);
    u32 r = bits + 0x7fffu + ((bits >> 16) & 1u);
    return r >> 16;
}
__device__ __forceinline__ u32 pack2(float a, float b) { return f2b(a) | (f2b(b) << 16); }

// ---------------------------------------------------------------------------
// Setup: blocks 0/1 detect dtype of x/W (flag=1 -> bf16; fp32 in this
// harness, kept for robustness); blocks 2..17 zero bbp.
__global__ __launch_bounds__(256) void k_setup(const u32* __restrict__ x,
                                               const u32* __restrict__ W,
                                               int* __restrict__ flags,
                                               float* __restrict__ bbp) {
    int blk = blockIdx.x, t = threadIdx.x;
    if (blk < 2) {
        __shared__ int red[4];
        const u32* p = blk ? W : x;
        int cnt = 0;
        for (int i = t; i < 2048; i += 256) {
            u32 e = (p[i] >> 7) & 0xFF;
            cnt += (e >= 0x60 && e <= 0x8F) ? 1 : 0;
        }
#pragma unroll
        for (int o = 32; o > 0; o >>= 1) cnt += __shfl_down(cnt, o, 64);
        if ((t & 63) == 0) red[t >> 6] = cnt;
        __syncthreads();
        if (t == 0) flags[blk] = ((red[0] + red[1] + red[2] + red[3]) > 1228) ? 1 : 0;
    } else {
        int base = (blk - 2) * 4096 + t;
#pragma unroll
        for (int r = 0; r < 16; ++r) bbp[base + r * 256] = 0.f;
    }
}

// ---------------------------------------------------------------------------
// xA[b][c][u] packed bf16 from x[b][u][c]  (A-operand for gemmA: k=(c,u)).
__global__ __launch_bounds__(256) void k_build_xA(const void* __restrict__ x,
                                                  u16* __restrict__ xA,
                                                  const int* __restrict__ flag) {
    int b = blockIdx.x >> 3;
    int c = (blockIdx.x & 7) * 256 + threadIdx.x;
    uint4 p;
    if (*flag) {
        const u16* xh = (const u16*)x + (size_t)b * UU * CC;
        u16 v[8];
#pragma unroll
        for (int u = 0; u < 8; ++u) v[u] = xh[u * CC + c];
        p.x = (u32)v[0] | ((u32)v[1] << 16);
        p.y = (u32)v[2] | ((u32)v[3] << 16);
        p.z = (u32)v[4] | ((u32)v[5] << 16);
        p.w = (u32)v[6] | ((u32)v[7] << 16);
    } else {
        const float* xf = (const float*)x + (size_t)b * UU * CC;
        float v[8];
#pragma unroll
        for (int u = 0; u < 8; ++u) v[u] = xf[u * CC + c];
        p.x = pack2(v[0], v[1]);
        p.y = pack2(v[2], v[3]);
        p.z = pack2(v[4], v[5]);
        p.w = pack2(v[6], v[7]);
    }
    ((uint4*)xA)[(size_t)b * CC + c] = p;
}

// ---------------------------------------------------------------------------
// xB[u][c][b] packed bf16 from x[b][u][c]  (B-operand for gemmB1: rows=c, k=b).
__global__ __launch_bounds__(256) void k_build_xB(const void* __restrict__ x,
                                                  u16* __restrict__ xB,
                                                  const int* __restrict__ flag) {
    __shared__ float lds[16][129];
    int u = blockIdx.x >> 7;
    int c0 = (blockIdx.x & 127) * 16;
    int t = threadIdx.x;
    int b = t >> 1, h = t & 1;
    size_t row = ((size_t)b * UU + u) * CC + c0;
    if (*flag) {
        const u16* xh = (const u16*)x + row + h * 8;
#pragma unroll
        for (int e = 0; e < 8; ++e) lds[h * 8 + e][b] = bflo((u32)xh[e]);
    } else {
        const float4* x4 = (const float4*)((const float*)x + row);
        float4 lo = x4[h * 2], hi = x4[h * 2 + 1];
        lds[h * 8 + 0][b] = lo.x; lds[h * 8 + 1][b] = lo.y;
        lds[h * 8 + 2][b] = lo.z; lds[h * 8 + 3][b] = lo.w;
        lds[h * 8 + 4][b] = hi.x; lds[h * 8 + 5][b] = hi.y;
        lds[h * 8 + 6][b] = hi.z; lds[h * 8 + 7][b] = hi.w;
    }
    __syncthreads();
    int ci = t >> 4, k8 = t & 15;
    uint4 p;
    p.x = pack2(lds[ci][k8 * 8 + 0], lds[ci][k8 * 8 + 1]);
    p.y = pack2(lds[ci][k8 * 8 + 2], lds[ci][k8 * 8 + 3]);
    p.z = pack2(lds[ci][k8 * 8 + 4], lds[ci][k8 * 8 + 5]);
    p.w = pack2(lds[ci][k8 * 8 + 6], lds[ci][k8 * 8 + 7]);
    ((uint4*)xB)[((size_t)u * CC + c0 + ci) * 16 + k8] = p;
}

// ---------------------------------------------------------------------------
// Wn[n=(j*16+s)][k8=c] = bf16(W[c,j,s,u]), u packed in uint4. Built ONCE.
__global__ __launch_bounds__(256) void k_build_Wn(const void* __restrict__ W,
                                                  u16* __restrict__ Wn,
                                                  const int* __restrict__ flag) {
    __shared__ uint4 lds[16][129];
    int ct = blockIdx.x & 127, nt = blockIdx.x >> 7;
    int c0 = ct * 16, n0 = nt * 128;
    int t = threadIdx.x;
    int isbf = *flag;
    for (int q = t; q < 2048; q += 256) {
        int ci = q >> 7, ni = q & 127;
        size_t widx = (size_t)(c0 + ci) * 512 + n0 + ni;
        uint4 o;
        if (isbf) {
            o = ((const uint4*)W)[widx];
        } else {
            const float4* Wf = (const float4*)W;
            float4 lo = Wf[2 * widx], hi = Wf[2 * widx + 1];
            o.x = pack2(lo.x, lo.y);
            o.y = pack2(lo.z, lo.w);
            o.z = pack2(hi.x, hi.y);
            o.w = pack2(hi.z, hi.w);
        }
        lds[ci][ni] = o;
    }
    __syncthreads();
    for (int q = t; q < 2048; q += 256) {
        int ni = q >> 4, ci = q & 15;
        ((uint4*)Wn)[(size_t)(n0 + ni) * 2048 + c0 + ci] = lds[ci][ni];
    }
}

// ---------------------------------------------------------------------------
// Softmax over C for each j; bbp/ccp layout [j][c].
__global__ __launch_bounds__(256) void k_softmax(const float* __restrict__ bbp,
                                                 float* __restrict__ ccp) {
    int j = blockIdx.x, t = threadIdx.x;
    __shared__ float red[4];
    __shared__ float bcast[2];
    const float* row = bbp + j * CC;
    float m = -1e30f;
    for (int c = t; c < CC; c += 256) m = fmaxf(m, row[c]);
#pragma unroll
    for (int o = 32; o > 0; o >>= 1) m = fmaxf(m, __shfl_down(m, o, 64));
    if ((t & 63) == 0) red[t >> 6] = m;
    __syncthreads();
    if (t == 0) bcast[0] = fmaxf(fmaxf(red[0], red[1]), fmaxf(red[2], red[3]));
    __syncthreads();
    float mm = bcast[0];
    float ssum = 0.f;
    for (int c = t; c < CC; c += 256) ssum += expf(row[c] - mm);
#pragma unroll
    for (int o = 32; o > 0; o >>= 1) ssum += __shfl_down(ssum, o, 64);
    if ((t & 63) == 0) red[t >> 6] = ssum;
    __syncthreads();
    if (t == 0) bcast[1] = red[0] + red[1] + red[2] + red[3];
    __syncthreads();
    float inv = 1.0f / bcast[1];
    for (int c = t; c < CC; c += 256) ccp[j * CC + c] = expf(row[c] - mm) * inv;
}

// ---------------------------------------------------------------------------
// bmatlite: Bm[n][c] = bf16( cc[j(n),c] * Wn[n][c] ). Pure stream, no LDS.
__global__ __launch_bounds__(256) void k_bmatlite(const u16* __restrict__ Wn,
                                                  const float* __restrict__ ccp,
                                                  u16* __restrict__ Bm) {
    int g = blockIdx.x * 256 + threadIdx.x;  // [0, 1048576)
    int n = g >> 11, c = g & 2047;
    uint4 p = ((const uint4*)Wn)[g];
    float cw = ccp[(n >> 4) * CC + c];
    uint4 o;
    o.x = pack2(bflo(p.x) * cw, bfhi(p.x) * cw);
    o.y = pack2(bflo(p.y) * cw, bfhi(p.y) * cw);
    o.z = pack2(bflo(p.z) * cw, bfhi(p.z) * cw);
    o.w = pack2(bflo(p.w) * cw, bfhi(p.w) * cw);
    ((uint4*)Bm)[g] = o;
}

// ---------------------------------------------------------------------------
// gemmA: spart[sl][b][n] = sum_{k in slice} xA[b][k] * Bmat[n][k].
// 32 K-slices (K=512 each), 512 blocks x 4 waves = 2048 waves (2/SIMD);
// wave = 2m x 2n tiles (16x16x32 bf16).
__global__ __launch_bounds__(256) void k_gemmA(const u16* __restrict__ xA,
                                               const u16* __restrict__ Bmat,
                                               float* __restrict__ spart) {
    const bf16x8* A8 = (const bf16x8*)xA;
    const bf16x8* B8 = (const bf16x8*)Bmat;
    int t = threadIdx.x;
    int w = t >> 6, lane = t & 63;
    int gw = blockIdx.x * 4 + w;       // [0,2048)
    int sl = gw >> 6, rest = gw & 63;  // slice, then 4 mg x 16 ng
    int mg = rest & 3, ng = rest >> 2;
    int ln = lane & 15, quad = lane >> 4;
    int rowA0 = (mg * 32 + ln) * 2048;
    int rowA1 = rowA0 + 16 * 2048;
    int rowB0 = (ng * 32 + ln) * 2048;
    int rowB1 = rowB0 + 16 * 2048;
    int kk = sl * 64 + quad;
    f32x4 acc00 = {0.f, 0.f, 0.f, 0.f};
    f32x4 acc01 = acc00, acc10 = acc00, acc11 = acc00;
#pragma unroll 4
    for (int step = 0; step < 16; ++step) {
        bf16x8 a0 = A8[rowA0 + kk];
        bf16x8 a1 = A8[rowA1 + kk];
        bf16x8 b0 = B8[rowB0 + kk];
        bf16x8 b1 = B8[rowB1 + kk];
        kk += 4;
        acc00 = __builtin_amdgcn_mfma_f32_16x16x32_bf16(a0, b0, acc00, 0, 0, 0);
        acc01 = __builtin_amdgcn_mfma_f32_16x16x32_bf16(a0, b1, acc01, 0, 0, 0);
        acc10 = __builtin_amdgcn_mfma_f32_16x16x32_bf16(a1, b0, acc10, 0, 0, 0);
        acc11 = __builtin_amdgcn_mfma_f32_16x16x32_bf16(a1, b1, acc11, 0, 0, 0);
    }
    float* outp = spart + sl * (BB * JJ * SS);
    int b0r = mg * 32 + quad * 4;
    int n00 = ng * 32 + ln;
#pragma unroll
    for (int r = 0; r < 4; ++r) {
        int b = b0r + r;
        outp[b * 512 + n00] = acc00[r];
        outp[b * 512 + n00 + 16] = acc01[r];
        outp[(b + 16) * 512 + n00] = acc10[r];
        outp[(b + 16) * 512 + n00 + 16] = acc11[r];
    }
}

// ---------------------------------------------------------------------------
// rsq: fused 32-slice reduce + squash (norm over J, reference axis=1).
// Grid 128 (one block per b) x 512 threads (one per n). scale_pre = 1/2048
// for it0 (uniform cc folded out of the GEMM), else 1.
__global__ __launch_bounds__(512) void k_rsq(const float* __restrict__ spart,
                                             u16* __restrict__ vB,
                                             float* __restrict__ out,
                                             float scale_pre, int write_out) {
    __shared__ float s[512];
    __shared__ float sc[16];
    int b = blockIdx.x, n = threadIdx.x;
    float v = 0.f;
#pragma unroll
    for (int sl = 0; sl < 32; ++sl) v += spart[sl * (BB * JJ * SS) + b * 512 + n];
    v *= scale_pre;
    s[n] = v;
    __syncthreads();
    if (n < 16) {
        float msq = 0.f;
#pragma unroll
        for (int jj = 0; jj < 32; ++jj) {
            float t = s[jj * 16 + n];
            msq = fmaf(t, t, msq);
        }
        sc[n] = msq / ((1.f + msq) * sqrtf(fmaxf(msq, 1e-30f)));
    }
    __syncthreads();
    float vv = s[n] * sc[n & 15];
    vB[n * BB + b] = (u16)f2b(vv);
    if (write_out) out[b * 512 + n] = vv;
}

// ---------------------------------------------------------------------------
// gemmB1: G[u][n][c] = sum_b vB[n][b] * xB[u][c][b]  (bf16 out; aliases Bm).
// 2048 blocks x 4 waves; wave = (u, 32n x 32c tile), K=128.
__global__ __launch_bounds__(256) void k_gemmB1(const u16* __restrict__ vB,
                                                const u16* __restrict__ xB,
                                                u16* __restrict__ G) {
    const bf16x8* A8 = (const bf16x8*)vB;
    const bf16x8* B8 = (const bf16x8*)xB;
    int t = threadIdx.x;
    int w = t >> 6, lane = t & 63;
    int gw = blockIdx.x * 4 + w;  // [0,8192)
    int u = gw >> 10, rest = gw & 1023;
    int n0 = (rest & 15) * 32, c0 = (rest >> 4) * 32;
    int ln = lane & 15, quad = lane >> 4;
    bf16x8 av[2][4], bx[2][4];
#pragma unroll
    for (int mt = 0; mt < 2; ++mt)
#pragma unroll
        for (int st = 0; st < 4; ++st)
            av[mt][st] = A8[(n0 + mt * 16 + ln) * 16 + quad + 4 * st];
#pragma unroll
    for (int ct = 0; ct < 2; ++ct)
#pragma unroll
        for (int st = 0; st < 4; ++st)
            bx[ct][st] = B8[((size_t)u * CC + c0 + ct * 16 + ln) * 16 + quad + 4 * st];
    f32x4 acc[2][2];
    acc[0][0] = {0.f, 0.f, 0.f, 0.f};
    acc[0][1] = acc[0][0]; acc[1][0] = acc[0][0]; acc[1][1] = acc[0][0];
#pragma unroll
    for (int st = 0; st < 4; ++st)
#pragma unroll
        for (int mt = 0; mt < 2; ++mt)
#pragma unroll
            for (int ct = 0; ct < 2; ++ct)
                acc[mt][ct] = __builtin_amdgcn_mfma_f32_16x16x32_bf16(
                    av[mt][st], bx[ct][st], acc[mt][ct], 0, 0, 0);
#pragma unroll
    for (int mt = 0; mt < 2; ++mt)
#pragma unroll
        for (int ct = 0; ct < 2; ++ct)
#pragma unroll
            for (int r = 0; r < 4; ++r) {
                int n = n0 + mt * 16 + quad * 4 + r;
                int c = c0 + ct * 16 + ln;
                G[((size_t)u * 512 + n) * 2048 + c] = (u16)f2b(acc[mt][ct][r]);
            }
}

// ---------------------------------------------------------------------------
// bbsum: bb[j][c] += (1/B) sum_{s,u} W[c][j*16+s][u] * G[u][j*16+s][c].
// Grid 1024 = 32 j x 16 c-chunks(128) x 2 s-halves; atomicAdd (2-way).
__global__ __launch_bounds__(256) void k_bbsum(const void* __restrict__ W,
                                               const u16* __restrict__ G,
                                               float* __restrict__ bbp,
                                               const int* __restrict__ wflag) {
    __shared__ u32 Wlds[128][33];  // [ci][s8*4 + upair], pad 33
    __shared__ float red[4][128];
    int j = blockIdx.x & 31;
    int c0 = ((blockIdx.x >> 5) & 15) * 128;
    int sh = blockIdx.x >> 9;  // 0/1: s-half
    int t = threadIdx.x;
    int isbf = *wflag;
#pragma unroll
    for (int it = 0; it < 8; ++it) {
        int q = t + it * 256;
        int ci = q >> 4, f4 = q & 15;  // f4 over 8s x 2 upair-pairs
        size_t fbase = ((size_t)(c0 + ci) * 512 + j * 16 + sh * 8) * 8 + f4 * 4;
        u32 p0, p1;
        if (isbf) {
            const u32* W32 = (const u32*)W;
            p0 = W32[fbase >> 1];
            p1 = W32[(fbase >> 1) + 1];
        } else {
            float4 f = ((const float4*)W)[fbase >> 2];
            p0 = pack2(f.x, f.y);
            p1 = pack2(f.z, f.w);
        }
        Wlds[ci][f4 * 2] = p0;
        Wlds[ci][f4 * 2 + 1] = p1;
    }
    __syncthreads();
    int w = t >> 6, cp = t & 63;  // wave w owns u {2w,2w+1}; thread 2 c's
    const u32* G32 = (const u32*)G;
    float acc0 = 0.f, acc1 = 0.f;
    int u0 = 2 * w;
#pragma unroll
    for (int s = 0; s < 8; ++s) {
        u32 wl = Wlds[2 * cp][s * 4 + w];
        u32 wh = Wlds[2 * cp + 1][s * 4 + w];
        int n = j * 16 + sh * 8 + s;
        u32 g0 = G32[((size_t)u0 * 512 + n) * 1024 + (c0 >> 1) + cp];
        u32 g1 = G32[((size_t)(u0 + 1) * 512 + n) * 1024 + (c0 >> 1) + cp];
        acc0 = fmaf(bflo(wl), bflo(g0), acc0);
        acc0 = fmaf(bfhi(wl), bflo(g1), acc0);
        acc1 = fmaf(bflo(wh), bfhi(g0), acc1);
        acc1 = fmaf(bfhi(wh), bfhi(g1), acc1);
    }
    red[w][2 * cp] = acc0;
    red[w][2 * cp + 1] = acc1;
    __syncthreads();
    if (t < 128) {
        float sum = red[0][t] + red[1][t] + red[2][t] + red[3][t];
        atomicAdd(&bbp[j * CC + c0 + t], sum * (1.0f / BB));
    }
}

// ---------------------------------------------------------------------------
extern "C" void kernel_launch(void* const* d_in, const int* in_sizes, int n_in,
                              void* d_out, int out_size, void* d_ws, size_t ws_size,
                              hipStream_t stream) {
    const void* x = d_in[0];
    const void* W = d_in[1];
    if (in_sizes[0] == CC * JJ * SS * UU) {  // robustness: order by size
        x = d_in[1];
        W = d_in[0];
    }
    float* out = (float*)d_out;  // fp32 output

    char* ws = (char*)d_ws;
    u16* Bm = (u16*)ws;                         // 16 MiB (aliased by G)
    u16* G = (u16*)ws;
    u16* xA = (u16*)(ws + (16u << 20));         // 4 MiB
    u16* xB = (u16*)(ws + (20u << 20));         // 4 MiB
    u16* Wn = (u16*)(ws + (24u << 20));         // 16 MiB
    float* spart = (float*)(ws + (40u << 20));  // 8 MiB (32 slices)
    size_t b48 = (size_t)48u << 20;
    u16* vB = (u16*)(ws + b48);                 // 128 KiB
    float* bbp = (float*)(ws + b48 + 131072);   // 256 KiB
    float* ccp = (float*)(ws + b48 + 393216);   // 256 KiB
    int* flags = (int*)(ws + b48 + 655360);

    k_setup<<<18, 256, 0, stream>>>((const u32*)x, (const u32*)W, flags, bbp);
    k_build_xA<<<1024, 256, 0, stream>>>(x, xA, flags + 0);
    k_build_xB<<<1024, 256, 0, stream>>>(x, xB, flags + 0);
    k_build_Wn<<<512, 256, 0, stream>>>(W, Wn, flags + 1);

    for (int it = 0; it < 3; ++it) {
        const u16* Bsrc = Wn;
        float scale_pre = 1.0f / 2048.0f;
        if (it > 0) {
            k_softmax<<<32, 256, 0, stream>>>(bbp, ccp);
            k_bmatlite<<<4096, 256, 0, stream>>>(Wn, ccp, Bm);
            Bsrc = Bm;
            scale_pre = 1.0f;
        }
        k_gemmA<<<512, 256, 0, stream>>>(xA, Bsrc, spart);
        k_rsq<<<128, 512, 0, stream>>>(spart, vB, out, scale_pre, it == 2 ? 1 : 0);
        if (it < 2) {
            k_gemmB1<<<2048, 256, 0, stream>>>(vB, xB, G);
            k_bbsum<<<1024, 256, 0, stream>>>(W, G, bbp, flags + 1);
        }
    }
}

// Round 11
// 215.403 us; speedup vs baseline: 2.0081x; 1.1335x over previous
//
#include <hip/hip_runtime.h>
#include <hip/hip_bf16.h>

// Problem: x [B,U,C] fp32, W [1,C,J,S,U] fp32, out [B,J,S,1] fp32.
// passA: bf16 MFMA GEMM s = xA · (cc*Wn)^T with the cc-multiply fused into the
//        K-loop (per-fragment scalar: B-tile rows share j; fragment = one c).
// passB: bf16 MFMA GEMM G[u][n][c] = sum_b vB[n][b] xB[u][c][b], then
//        coalesced contraction bb[j][c] += (1/B) sum_{s,u} Wn*G.
#define BB 128
#define UU 8
#define CC 2048
#define JJ 32
#define SS 16

typedef unsigned int u32;
typedef unsigned short u16;
typedef __attribute__((ext_vector_type(8))) short bf16x8;
typedef __attribute__((ext_vector_type(4))) float f32x4;

__device__ __forceinline__ float bflo(u32 p) { return __uint_as_float(p << 16); }
__device__ __forceinline__ float bfhi(u32 p) { return __uint_as_float(p & 0xffff0000u); }
__device__ __forceinline__ u32 f2b(float f) {  // RNE fp32->bf16 bits
    u32 bits = __float_as_uint(f);
    u32 r = bits + 0x7fffu + ((bits >> 16) & 1u);
    return r >> 16;
}
__device__ __forceinline__ u32 pack2(float a, float b) { return f2b(a) | (f2b(b) << 16); }
__device__ __forceinline__ uint4 scale4(uint4 p, float cw) {
    uint4 o;
    o.x = pack2(bflo(p.x) * cw, bfhi(p.x) * cw);
    o.y = pack2(bflo(p.y) * cw, bfhi(p.y) * cw);
    o.z = pack2(bflo(p.z) * cw, bfhi(p.z) * cw);
    o.w = pack2(bflo(p.w) * cw, bfhi(p.w) * cw);
    return o;
}

// ---------------------------------------------------------------------------
// prep (one dispatch): blocks 0..1023 build xA[b][c][u] bf16 (gemmA A-operand);
// 1024..2047 build xB[u][c][b] bf16 (gemmB1 B-operand); 2048..2559 build
// Wn[n=(j,s)][c][u] bf16 (gemmA B / bbsum W); 2560..2575 zero bbp.
__global__ __launch_bounds__(256) void k_prep(const float* __restrict__ x,
                                              const float* __restrict__ W,
                                              u16* __restrict__ xA,
                                              u16* __restrict__ xB,
                                              u16* __restrict__ Wn,
                                              float* __restrict__ bbp) {
    __shared__ uint4 ldsu[16][129];
    int blk = blockIdx.x, t = threadIdx.x;
    if (blk < 1024) {
        int b = blk >> 3;
        int c = (blk & 7) * 256 + t;
        const float* xf = x + (size_t)b * UU * CC;
        float v[8];
#pragma unroll
        for (int u = 0; u < 8; ++u) v[u] = xf[u * CC + c];
        uint4 p;
        p.x = pack2(v[0], v[1]);
        p.y = pack2(v[2], v[3]);
        p.z = pack2(v[4], v[5]);
        p.w = pack2(v[6], v[7]);
        ((uint4*)xA)[(size_t)b * CC + c] = p;
    } else if (blk < 2048) {
        int bb2 = blk - 1024;
        int u = bb2 >> 7, c0 = (bb2 & 127) * 16;
        float* ldsf = (float*)ldsu;
        int b = t >> 1, h = t & 1;
        const float4* x4 = (const float4*)(x + ((size_t)b * UU + u) * CC + c0);
        float4 lo = x4[h * 2], hi = x4[h * 2 + 1];
        ldsf[(h * 8 + 0) * 129 + b] = lo.x; ldsf[(h * 8 + 1) * 129 + b] = lo.y;
        ldsf[(h * 8 + 2) * 129 + b] = lo.z; ldsf[(h * 8 + 3) * 129 + b] = lo.w;
        ldsf[(h * 8 + 4) * 129 + b] = hi.x; ldsf[(h * 8 + 5) * 129 + b] = hi.y;
        ldsf[(h * 8 + 6) * 129 + b] = hi.z; ldsf[(h * 8 + 7) * 129 + b] = hi.w;
        __syncthreads();
        int ci = t >> 4, k8 = t & 15;
        const float* r = ldsf + ci * 129 + k8 * 8;
        uint4 p;
        p.x = pack2(r[0], r[1]);
        p.y = pack2(r[2], r[3]);
        p.z = pack2(r[4], r[5]);
        p.w = pack2(r[6], r[7]);
        ((uint4*)xB)[((size_t)u * CC + c0 + ci) * 16 + k8] = p;
    } else if (blk < 2560) {
        int bb2 = blk - 2048;
        int ct = bb2 & 127, nt = bb2 >> 7;
        int c0 = ct * 16, n0 = nt * 128;
        const float4* Wf = (const float4*)W;
        for (int q = t; q < 2048; q += 256) {
            int ci = q >> 7, ni = q & 127;
            size_t widx = (size_t)(c0 + ci) * 512 + n0 + ni;
            float4 lo = Wf[2 * widx], hi = Wf[2 * widx + 1];
            uint4 o;
            o.x = pack2(lo.x, lo.y);
            o.y = pack2(lo.z, lo.w);
            o.z = pack2(hi.x, hi.y);
            o.w = pack2(hi.z, hi.w);
            ldsu[ci][ni] = o;
        }
        __syncthreads();
        for (int q = t; q < 2048; q += 256) {
            int ni = q >> 4, ci = q & 15;
            ((uint4*)Wn)[(size_t)(n0 + ni) * 2048 + c0 + ci] = ldsu[ci][ni];
        }
    } else {
        int base = (blk - 2560) * 4096 + t;
#pragma unroll
        for (int r = 0; r < 16; ++r) bbp[base + r * 256] = 0.f;
    }
}

// ---------------------------------------------------------------------------
// Softmax over C for each j; bbp/ccp layout [j][c].
__global__ __launch_bounds__(256) void k_softmax(const float* __restrict__ bbp,
                                                 float* __restrict__ ccp) {
    int j = blockIdx.x, t = threadIdx.x;
    __shared__ float red[4];
    __shared__ float bcast[2];
    const float* row = bbp + j * CC;
    float m = -1e30f;
    for (int c = t; c < CC; c += 256) m = fmaxf(m, row[c]);
#pragma unroll
    for (int o = 32; o > 0; o >>= 1) m = fmaxf(m, __shfl_down(m, o, 64));
    if ((t & 63) == 0) red[t >> 6] = m;
    __syncthreads();
    if (t == 0) bcast[0] = fmaxf(fmaxf(red[0], red[1]), fmaxf(red[2], red[3]));
    __syncthreads();
    float mm = bcast[0];
    float ssum = 0.f;
    for (int c = t; c < CC; c += 256) ssum += expf(row[c] - mm);
#pragma unroll
    for (int o = 32; o > 0; o >>= 1) ssum += __shfl_down(ssum, o, 64);
    if ((t & 63) == 0) red[t >> 6] = ssum;
    __syncthreads();
    if (t == 0) bcast[1] = red[0] + red[1] + red[2] + red[3];
    __syncthreads();
    float inv = 1.0f / bcast[1];
    for (int c = t; c < CC; c += 256) ccp[j * CC + c] = expf(row[c] - mm) * inv;
}

// ---------------------------------------------------------------------------
// gemmA (cc fused): spart[sl][b][n] = sum_{k in slice} xA[b][k] *
//   (cc[j(n),c(k)] * Wn[n][k]). B-tile rows share j; fragment = one c, so the
// cc factor is a per-fragment scalar. use_cc=0 -> raw Wn (it0: cc uniform,
// 1/2048 applied in rsq). 32 K-slices, 512 blocks x 4 waves (2 waves/SIMD).
__global__ __launch_bounds__(256) void k_gemmA(const u16* __restrict__ xA,
                                               const u16* __restrict__ Wn,
                                               const float* __restrict__ ccp,
                                               int use_cc,
                                               float* __restrict__ spart) {
    const bf16x8* A8 = (const bf16x8*)xA;
    const uint4* B4 = (const uint4*)Wn;
    int t = threadIdx.x;
    int w = t >> 6, lane = t & 63;
    int gw = blockIdx.x * 4 + w;       // [0,2048)
    int sl = gw >> 6, rest = gw & 63;  // slice, then 4 mg x 16 ng
    int mg = rest & 3, ng = rest >> 2;
    int ln = lane & 15, quad = lane >> 4;
    int rowA0 = (mg * 32 + ln) * 2048;
    int rowA1 = rowA0 + 16 * 2048;
    int rowB0 = (ng * 32 + ln) * 2048;
    int rowB1 = rowB0 + 16 * 2048;
    const float* cc0 = ccp + (2 * ng) * CC;  // j uniform per 16-row B-tile
    const float* cc1 = cc0 + CC;
    int kk = sl * 64 + quad;
    f32x4 acc00 = {0.f, 0.f, 0.f, 0.f};
    f32x4 acc01 = acc00, acc10 = acc00, acc11 = acc00;
#pragma unroll 4
    for (int step = 0; step < 16; ++step) {
        bf16x8 a0 = A8[rowA0 + kk];
        bf16x8 a1 = A8[rowA1 + kk];
        uint4 wb0 = B4[rowB0 + kk];
        uint4 wb1 = B4[rowB1 + kk];
        if (use_cc) {
            float cw0 = cc0[kk];  // c == kk (fragment granule = one c)
            float cw1 = cc1[kk];
            wb0 = scale4(wb0, cw0);
            wb1 = scale4(wb1, cw1);
        }
        bf16x8 b0 = __builtin_bit_cast(bf16x8, wb0);
        bf16x8 b1 = __builtin_bit_cast(bf16x8, wb1);
        kk += 4;
        acc00 = __builtin_amdgcn_mfma_f32_16x16x32_bf16(a0, b0, acc00, 0, 0, 0);
        acc01 = __builtin_amdgcn_mfma_f32_16x16x32_bf16(a0, b1, acc01, 0, 0, 0);
        acc10 = __builtin_amdgcn_mfma_f32_16x16x32_bf16(a1, b0, acc10, 0, 0, 0);
        acc11 = __builtin_amdgcn_mfma_f32_16x16x32_bf16(a1, b1, acc11, 0, 0, 0);
    }
    float* outp = spart + sl * (BB * JJ * SS);
    int b0r = mg * 32 + quad * 4;
    int n00 = ng * 32 + ln;
#pragma unroll
    for (int r = 0; r < 4; ++r) {
        int b = b0r + r;
        outp[b * 512 + n00] = acc00[r];
        outp[b * 512 + n00 + 16] = acc01[r];
        outp[(b + 16) * 512 + n00] = acc10[r];
        outp[(b + 16) * 512 + n00 + 16] = acc11[r];
    }
}

// ---------------------------------------------------------------------------
// rsq: fused 32-slice reduce + squash (norm over J, reference axis=1).
// Grid 128 (one block per b) x 512 threads (one per n). scale_pre = 1/2048
// for it0 (uniform cc folded out of the GEMM), else 1.
__global__ __launch_bounds__(512) void k_rsq(const float* __restrict__ spart,
                                             u16* __restrict__ vB,
                                             float* __restrict__ out,
                                             float scale_pre, int write_out) {
    __shared__ float s[512];
    __shared__ float sc[16];
    int b = blockIdx.x, n = threadIdx.x;
    float v = 0.f;
#pragma unroll
    for (int sl = 0; sl < 32; ++sl) v += spart[sl * (BB * JJ * SS) + b * 512 + n];
    v *= scale_pre;
    s[n] = v;
    __syncthreads();
    if (n < 16) {
        float msq = 0.f;
#pragma unroll
        for (int jj = 0; jj < 32; ++jj) {
            float tv = s[jj * 16 + n];
            msq = fmaf(tv, tv, msq);
        }
        sc[n] = msq / ((1.f + msq) * sqrtf(fmaxf(msq, 1e-30f)));
    }
    __syncthreads();
    float vv = s[n] * sc[n & 15];
    vB[n * BB + b] = (u16)f2b(vv);
    if (write_out) out[b * 512 + n] = vv;
}

// ---------------------------------------------------------------------------
// gemmB1: G[u][n][c] = sum_b vB[n][b] * xB[u][c][b]  (bf16 out).
// 2048 blocks x 4 waves; wave = (u, 32n x 32c tile), K=128.
__global__ __launch_bounds__(256) void k_gemmB1(const u16* __restrict__ vB,
                                                const u16* __restrict__ xB,
                                                u16* __restrict__ G) {
    const bf16x8* A8 = (const bf16x8*)vB;
    const bf16x8* B8 = (const bf16x8*)xB;
    int t = threadIdx.x;
    int w = t >> 6, lane = t & 63;
    int gw = blockIdx.x * 4 + w;  // [0,8192)
    int u = gw >> 10, rest = gw & 1023;
    int n0 = (rest & 15) * 32, c0 = (rest >> 4) * 32;
    int ln = lane & 15, quad = lane >> 4;
    bf16x8 av[2][4], bx[2][4];
#pragma unroll
    for (int mt = 0; mt < 2; ++mt)
#pragma unroll
        for (int st = 0; st < 4; ++st)
            av[mt][st] = A8[(n0 + mt * 16 + ln) * 16 + quad + 4 * st];
#pragma unroll
    for (int ct = 0; ct < 2; ++ct)
#pragma unroll
        for (int st = 0; st < 4; ++st)
            bx[ct][st] = B8[((size_t)u * CC + c0 + ct * 16 + ln) * 16 + quad + 4 * st];
    f32x4 acc[2][2];
    acc[0][0] = {0.f, 0.f, 0.f, 0.f};
    acc[0][1] = acc[0][0]; acc[1][0] = acc[0][0]; acc[1][1] = acc[0][0];
#pragma unroll
    for (int st = 0; st < 4; ++st)
#pragma unroll
        for (int mt = 0; mt < 2; ++mt)
#pragma unroll
            for (int ct = 0; ct < 2; ++ct)
                acc[mt][ct] = __builtin_amdgcn_mfma_f32_16x16x32_bf16(
                    av[mt][st], bx[ct][st], acc[mt][ct], 0, 0, 0);
#pragma unroll
    for (int mt = 0; mt < 2; ++mt)
#pragma unroll
        for (int ct = 0; ct < 2; ++ct)
#pragma unroll
            for (int r = 0; r < 4; ++r) {
                int n = n0 + mt * 16 + quad * 4 + r;
                int c = c0 + ct * 16 + ln;
                G[((size_t)u * 512 + n) * 2048 + c] = (u16)f2b(acc[mt][ct][r]);
            }
}

// ---------------------------------------------------------------------------
// bbsum: bb[j][c] += (1/B) sum_{s,u} Wn[(j,s)][c][u] * G[u][(j,s)][c].
// Grid 1024 = 32 j x 16 c-chunks(128) x 2 s-halves; atomicAdd (2-way).
// W staged from Wn (bf16, c-coalesced) — half the traffic of fp32 W.
__global__ __launch_bounds__(256) void k_bbsum(const u16* __restrict__ Wn,
                                               const u16* __restrict__ G,
                                               float* __restrict__ bbp) {
    __shared__ u32 Wlds[128][33];  // [ci][s8*4 + upair], pad 33
    __shared__ float red[4][128];
    int j = blockIdx.x & 31;
    int c0 = ((blockIdx.x >> 5) & 15) * 128;
    int sh = blockIdx.x >> 9;  // 0/1: s-half
    int t = threadIdx.x;
    const uint4* Wn4 = (const uint4*)Wn;
#pragma unroll
    for (int it = 0; it < 4; ++it) {
        int q = t + it * 256;          // [0,1024)
        int ci = q & 127, s = q >> 7;  // ci fastest -> coalesced uint4
        uint4 p = Wn4[(size_t)(j * 16 + sh * 8 + s) * 2048 + c0 + ci];
        Wlds[ci][s * 4 + 0] = p.x;
        Wlds[ci][s * 4 + 1] = p.y;
        Wlds[ci][s * 4 + 2] = p.z;
        Wlds[ci][s * 4 + 3] = p.w;
    }
    __syncthreads();
    int w = t >> 6, cp = t & 63;  // wave w owns u {2w,2w+1}; thread 2 c's
    const u32* G32 = (const u32*)G;
    float acc0 = 0.f, acc1 = 0.f;
    int u0 = 2 * w;
#pragma unroll
    for (int s = 0; s < 8; ++s) {
        u32 wl = Wlds[2 * cp][s * 4 + w];
        u32 wh = Wlds[2 * cp + 1][s * 4 + w];
        int n = j * 16 + sh * 8 + s;
        u32 g0 = G32[((size_t)u0 * 512 + n) * 1024 + (c0 >> 1) + cp];
        u32 g1 = G32[((size_t)(u0 + 1) * 512 + n) * 1024 + (c0 >> 1) + cp];
        acc0 = fmaf(bflo(wl), bflo(g0), acc0);
        acc0 = fmaf(bfhi(wl), bflo(g1), acc0);
        acc1 = fmaf(bflo(wh), bfhi(g0), acc1);
        acc1 = fmaf(bfhi(wh), bfhi(g1), acc1);
    }
    red[w][2 * cp] = acc0;
    red[w][2 * cp + 1] = acc1;
    __syncthreads();
    if (t < 128) {
        float sum = red[0][t] + red[1][t] + red[2][t] + red[3][t];
        atomicAdd(&bbp[j * CC + c0 + t], sum * (1.0f / BB));
    }
}

// ---------------------------------------------------------------------------
extern "C" void kernel_launch(void* const* d_in, const int* in_sizes, int n_in,
                              void* d_out, int out_size, void* d_ws, size_t ws_size,
                              hipStream_t stream) {
    const float* x = (const float*)d_in[0];
    const float* W = (const float*)d_in[1];
    if (in_sizes[0] == CC * JJ * SS * UU) {  // robustness: order by size
        x = (const float*)d_in[1];
        W = (const float*)d_in[0];
    }
    float* out = (float*)d_out;  // fp32 output

    char* ws = (char*)d_ws;
    u16* G = (u16*)ws;                          // 16 MiB
    u16* xA = (u16*)(ws + (16u << 20));         // 4 MiB
    u16* xB = (u16*)(ws + (20u << 20));         // 4 MiB
    u16* Wn = (u16*)(ws + (24u << 20));         // 16 MiB
    float* spart = (float*)(ws + (40u << 20));  // 8 MiB (32 slices)
    size_t b48 = (size_t)48u << 20;
    u16* vB = (u16*)(ws + b48);                 // 128 KiB
    float* bbp = (float*)(ws + b48 + 131072);   // 256 KiB
    float* ccp = (float*)(ws + b48 + 393216);   // 256 KiB

    k_prep<<<2576, 256, 0, stream>>>(x, W, xA, xB, Wn, bbp);

    for (int it = 0; it < 3; ++it) {
        if (it > 0) k_softmax<<<32, 256, 0, stream>>>(bbp, ccp);
        k_gemmA<<<512, 256, 0, stream>>>(xA, Wn, ccp, it > 0 ? 1 : 0, spart);
        k_rsq<<<128, 512, 0, stream>>>(spart, vB, out,
                                       it == 0 ? (1.0f / 2048.0f) : 1.0f,
                                       it == 2 ? 1 : 0);
        if (it < 2) {
            k_gemmB1<<<2048, 256, 0, stream>>>(vB, xB, G);
            k_bbsum<<<1024, 256, 0, stream>>>(Wn, G, bbp);
        }
    }
}

// Round 12
// 212.759 us; speedup vs baseline: 2.0331x; 1.0124x over previous
//
#include <hip/hip_runtime.h>
#include <hip/hip_bf16.h>

// Problem: x [B,U,C] fp32, W [1,C,J,S,U] fp32, out [B,J,S,1] fp32.
// passA: bf16 MFMA GEMM s = xA · (cc*Wn)^T, cc fused into the K-loop.
// passB: bf16 MFMA GEMM G[u][n][c] = sum_b vB[n][b] xB[u][c][b] with the
//        W∘G contraction fused in the epilogue (no G tensor): shfl-reduce
//        over s, atomicAdd into bb[j][c].
#define BB 128
#define UU 8
#define CC 2048
#define JJ 32
#define SS 16

typedef unsigned int u32;
typedef unsigned short u16;
typedef __attribute__((ext_vector_type(8))) short bf16x8;
typedef __attribute__((ext_vector_type(4))) float f32x4;

__device__ __forceinline__ float bflo(u32 p) { return __uint_as_float(p << 16); }
__device__ __forceinline__ float bfhi(u32 p) { return __uint_as_float(p & 0xffff0000u); }
__device__ __forceinline__ u32 f2b(float f) {  // RNE fp32->bf16 bits
    u32 bits = __float_as_uint(f);
    u32 r = bits + 0x7fffu + ((bits >> 16) & 1u);
    return r >> 16;
}
__device__ __forceinline__ u32 pack2(float a, float b) { return f2b(a) | (f2b(b) << 16); }
__device__ __forceinline__ uint4 scale4(uint4 p, float cw) {
    uint4 o;
    o.x = pack2(bflo(p.x) * cw, bfhi(p.x) * cw);
    o.y = pack2(bflo(p.y) * cw, bfhi(p.y) * cw);
    o.z = pack2(bflo(p.z) * cw, bfhi(p.z) * cw);
    o.w = pack2(bflo(p.w) * cw, bfhi(p.w) * cw);
    return o;
}

// ---------------------------------------------------------------------------
// prep (one dispatch): blocks 0..1023 build xA[b][c][u] bf16 (gemmA A-operand);
// 1024..2047 build xB[u][c][b] bf16 (gemmB B-operand); 2048..2559 build
// Wn[n=(j,s)][c][u] bf16 (gemmA B-operand / gemmB epilogue W); 2560..2575
// zero bbp.
__global__ __launch_bounds__(256) void k_prep(const float* __restrict__ x,
                                              const float* __restrict__ W,
                                              u16* __restrict__ xA,
                                              u16* __restrict__ xB,
                                              u16* __restrict__ Wn,
                                              float* __restrict__ bbp) {
    __shared__ uint4 ldsu[16][129];
    int blk = blockIdx.x, t = threadIdx.x;
    if (blk < 1024) {
        int b = blk >> 3;
        int c = (blk & 7) * 256 + t;
        const float* xf = x + (size_t)b * UU * CC;
        float v[8];
#pragma unroll
        for (int u = 0; u < 8; ++u) v[u] = xf[u * CC + c];
        uint4 p;
        p.x = pack2(v[0], v[1]);
        p.y = pack2(v[2], v[3]);
        p.z = pack2(v[4], v[5]);
        p.w = pack2(v[6], v[7]);
        ((uint4*)xA)[(size_t)b * CC + c] = p;
    } else if (blk < 2048) {
        int bb2 = blk - 1024;
        int u = bb2 >> 7, c0 = (bb2 & 127) * 16;
        float* ldsf = (float*)ldsu;
        int b = t >> 1, h = t & 1;
        const float4* x4 = (const float4*)(x + ((size_t)b * UU + u) * CC + c0);
        float4 lo = x4[h * 2], hi = x4[h * 2 + 1];
        ldsf[(h * 8 + 0) * 129 + b] = lo.x; ldsf[(h * 8 + 1) * 129 + b] = lo.y;
        ldsf[(h * 8 + 2) * 129 + b] = lo.z; ldsf[(h * 8 + 3) * 129 + b] = lo.w;
        ldsf[(h * 8 + 4) * 129 + b] = hi.x; ldsf[(h * 8 + 5) * 129 + b] = hi.y;
        ldsf[(h * 8 + 6) * 129 + b] = hi.z; ldsf[(h * 8 + 7) * 129 + b] = hi.w;
        __syncthreads();
        int ci = t >> 4, k8 = t & 15;
        const float* r = ldsf + ci * 129 + k8 * 8;
        uint4 p;
        p.x = pack2(r[0], r[1]);
        p.y = pack2(r[2], r[3]);
        p.z = pack2(r[4], r[5]);
        p.w = pack2(r[6], r[7]);
        ((uint4*)xB)[((size_t)u * CC + c0 + ci) * 16 + k8] = p;
    } else if (blk < 2560) {
        int bb2 = blk - 2048;
        int ct = bb2 & 127, nt = bb2 >> 7;
        int c0 = ct * 16, n0 = nt * 128;
        const float4* Wf = (const float4*)W;
        for (int q = t; q < 2048; q += 256) {
            int ci = q >> 7, ni = q & 127;
            size_t widx = (size_t)(c0 + ci) * 512 + n0 + ni;
            float4 lo = Wf[2 * widx], hi = Wf[2 * widx + 1];
            uint4 o;
            o.x = pack2(lo.x, lo.y);
            o.y = pack2(lo.z, lo.w);
            o.z = pack2(hi.x, hi.y);
            o.w = pack2(hi.z, hi.w);
            ldsu[ci][ni] = o;
        }
        __syncthreads();
        for (int q = t; q < 2048; q += 256) {
            int ni = q >> 4, ci = q & 15;
            ((uint4*)Wn)[(size_t)(n0 + ni) * 2048 + c0 + ci] = ldsu[ci][ni];
        }
    } else {
        int base = (blk - 2560) * 4096 + t;
#pragma unroll
        for (int r = 0; r < 16; ++r) bbp[base + r * 256] = 0.f;
    }
}

// ---------------------------------------------------------------------------
// Softmax over C for each j; bbp/ccp layout [j][c].
__global__ __launch_bounds__(256) void k_softmax(const float* __restrict__ bbp,
                                                 float* __restrict__ ccp) {
    int j = blockIdx.x, t = threadIdx.x;
    __shared__ float red[4];
    __shared__ float bcast[2];
    const float* row = bbp + j * CC;
    float m = -1e30f;
    for (int c = t; c < CC; c += 256) m = fmaxf(m, row[c]);
#pragma unroll
    for (int o = 32; o > 0; o >>= 1) m = fmaxf(m, __shfl_down(m, o, 64));
    if ((t & 63) == 0) red[t >> 6] = m;
    __syncthreads();
    if (t == 0) bcast[0] = fmaxf(fmaxf(red[0], red[1]), fmaxf(red[2], red[3]));
    __syncthreads();
    float mm = bcast[0];
    float ssum = 0.f;
    for (int c = t; c < CC; c += 256) ssum += expf(row[c] - mm);
#pragma unroll
    for (int o = 32; o > 0; o >>= 1) ssum += __shfl_down(ssum, o, 64);
    if ((t & 63) == 0) red[t >> 6] = ssum;
    __syncthreads();
    if (t == 0) bcast[1] = red[0] + red[1] + red[2] + red[3];
    __syncthreads();
    float inv = 1.0f / bcast[1];
    for (int c = t; c < CC; c += 256) ccp[j * CC + c] = expf(row[c] - mm) * inv;
}

// ---------------------------------------------------------------------------
// gemmA (cc fused): spart[sl][b][n] = sum_{k in slice} xA[b][k] *
//   (cc[j(n),c(k)] * Wn[n][k]). use_cc=0 -> raw Wn (it0: uniform cc, 1/2048
// applied in rsq). 32 K-slices, 512 blocks x 4 waves (2 waves/SIMD).
__global__ __launch_bounds__(256) void k_gemmA(const u16* __restrict__ xA,
                                               const u16* __restrict__ Wn,
                                               const float* __restrict__ ccp,
                                               int use_cc,
                                               float* __restrict__ spart) {
    const bf16x8* A8 = (const bf16x8*)xA;
    const uint4* B4 = (const uint4*)Wn;
    int t = threadIdx.x;
    int w = t >> 6, lane = t & 63;
    int gw = blockIdx.x * 4 + w;       // [0,2048)
    int sl = gw >> 6, rest = gw & 63;  // slice, then 4 mg x 16 ng
    int mg = rest & 3, ng = rest >> 2;
    int ln = lane & 15, quad = lane >> 4;
    int rowA0 = (mg * 32 + ln) * 2048;
    int rowA1 = rowA0 + 16 * 2048;
    int rowB0 = (ng * 32 + ln) * 2048;
    int rowB1 = rowB0 + 16 * 2048;
    const float* cc0 = ccp + (2 * ng) * CC;  // j uniform per 16-row B-tile
    const float* cc1 = cc0 + CC;
    int kk = sl * 64 + quad;
    f32x4 acc00 = {0.f, 0.f, 0.f, 0.f};
    f32x4 acc01 = acc00, acc10 = acc00, acc11 = acc00;
#pragma unroll 4
    for (int step = 0; step < 16; ++step) {
        bf16x8 a0 = A8[rowA0 + kk];
        bf16x8 a1 = A8[rowA1 + kk];
        uint4 wb0 = B4[rowB0 + kk];
        uint4 wb1 = B4[rowB1 + kk];
        if (use_cc) {
            float cw0 = cc0[kk];  // c == kk (fragment granule = one c)
            float cw1 = cc1[kk];
            wb0 = scale4(wb0, cw0);
            wb1 = scale4(wb1, cw1);
        }
        bf16x8 b0 = __builtin_bit_cast(bf16x8, wb0);
        bf16x8 b1 = __builtin_bit_cast(bf16x8, wb1);
        kk += 4;
        acc00 = __builtin_amdgcn_mfma_f32_16x16x32_bf16(a0, b0, acc00, 0, 0, 0);
        acc01 = __builtin_amdgcn_mfma_f32_16x16x32_bf16(a0, b1, acc01, 0, 0, 0);
        acc10 = __builtin_amdgcn_mfma_f32_16x16x32_bf16(a1, b0, acc10, 0, 0, 0);
        acc11 = __builtin_amdgcn_mfma_f32_16x16x32_bf16(a1, b1, acc11, 0, 0, 0);
    }
    float* outp = spart + sl * (BB * JJ * SS);
    int b0r = mg * 32 + quad * 4;
    int n00 = ng * 32 + ln;
#pragma unroll
    for (int r = 0; r < 4; ++r) {
        int b = b0r + r;
        outp[b * 512 + n00] = acc00[r];
        outp[b * 512 + n00 + 16] = acc01[r];
        outp[(b + 16) * 512 + n00] = acc10[r];
        outp[(b + 16) * 512 + n00 + 16] = acc11[r];
    }
}

// ---------------------------------------------------------------------------
// rsq: fused 32-slice reduce + squash (norm over J, reference axis=1).
// Grid 128 (one block per b) x 512 threads (one per n). scale_pre = 1/2048
// for it0 (uniform cc folded out of the GEMM), else 1.
__global__ __launch_bounds__(512) void k_rsq(const float* __restrict__ spart,
                                             u16* __restrict__ vB,
                                             float* __restrict__ out,
                                             float scale_pre, int write_out) {
    __shared__ float s[512];
    __shared__ float sc[16];
    int b = blockIdx.x, n = threadIdx.x;
    float v = 0.f;
#pragma unroll
    for (int sl = 0; sl < 32; ++sl) v += spart[sl * (BB * JJ * SS) + b * 512 + n];
    v *= scale_pre;
    s[n] = v;
    __syncthreads();
    if (n < 16) {
        float msq = 0.f;
#pragma unroll
        for (int jj = 0; jj < 32; ++jj) {
            float tv = s[jj * 16 + n];
            msq = fmaf(tv, tv, msq);
        }
        sc[n] = msq / ((1.f + msq) * sqrtf(fmaxf(msq, 1e-30f)));
    }
    __syncthreads();
    float vv = s[n] * sc[n & 15];
    vB[n * BB + b] = (u16)f2b(vv);
    if (write_out) out[b * 512 + n] = vv;
}

// ---------------------------------------------------------------------------
// gemmBf (fused): G[u][n][c] = sum_b vB[n][b] * xB[u][c][b] computed per-wave
// in registers; epilogue multiplies by Wn[n][c][u] (wave-uniform u), reduces
// over s (in-lane r + shfl over quad), atomicAdds (1/B)*sum into bb[j][c].
// 2048 blocks x 4 waves; wave = (u, 32n x 32c tile), K=128. No LDS.
__global__ __launch_bounds__(256) void k_gemmBf(const u16* __restrict__ vB,
                                                const u16* __restrict__ xB,
                                                const u16* __restrict__ Wn,
                                                float* __restrict__ bbp) {
    const bf16x8* A8 = (const bf16x8*)vB;
    const bf16x8* B8 = (const bf16x8*)xB;
    const uint4* Wn4 = (const uint4*)Wn;
    int t = threadIdx.x;
    int w = t >> 6, lane = t & 63;
    int gw = blockIdx.x * 4 + w;  // [0,8192)
    int u = gw >> 10, rest = gw & 1023;
    int nt = rest & 15, c0 = (rest >> 4) * 32;
    int n0 = nt * 32;
    int ln = lane & 15, quad = lane >> 4;
    bf16x8 av[2][4], bx[2][4];
#pragma unroll
    for (int mt = 0; mt < 2; ++mt)
#pragma unroll
        for (int st = 0; st < 4; ++st)
            av[mt][st] = A8[(n0 + mt * 16 + ln) * 16 + quad + 4 * st];
#pragma unroll
    for (int ct = 0; ct < 2; ++ct)
#pragma unroll
        for (int st = 0; st < 4; ++st)
            bx[ct][st] = B8[((size_t)u * CC + c0 + ct * 16 + ln) * 16 + quad + 4 * st];
    f32x4 acc[2][2];
    acc[0][0] = {0.f, 0.f, 0.f, 0.f};
    acc[0][1] = acc[0][0]; acc[1][0] = acc[0][0]; acc[1][1] = acc[0][0];
#pragma unroll
    for (int st = 0; st < 4; ++st)
#pragma unroll
        for (int mt = 0; mt < 2; ++mt)
#pragma unroll
            for (int ct = 0; ct < 2; ++ct)
                acc[mt][ct] = __builtin_amdgcn_mfma_f32_16x16x32_bf16(
                    av[mt][st], bx[ct][st], acc[mt][ct], 0, 0, 0);
    // Epilogue: lane holds G[n = n0+mt*16+quad*4+r][c = c0+ct*16+ln].
    // val = G * Wn[n][c][u]; sum over s = (quad,r); quad-0 lanes atomicAdd.
#pragma unroll
    for (int mt = 0; mt < 2; ++mt) {
        int j = 2 * nt + mt;
#pragma unroll
        for (int ct = 0; ct < 2; ++ct) {
            int c = c0 + ct * 16 + ln;
            float val = 0.f;
#pragma unroll
            for (int r = 0; r < 4; ++r) {
                int n = n0 + mt * 16 + quad * 4 + r;
                uint4 wp = Wn4[(size_t)n * 2048 + c];
                u32 warr[4] = {wp.x, wp.y, wp.z, wp.w};
                u32 ww = warr[u >> 1];
                float wv = (u & 1) ? bfhi(ww) : bflo(ww);
                val = fmaf(acc[mt][ct][r], wv, val);
            }
            val += __shfl_xor(val, 16, 64);
            val += __shfl_xor(val, 32, 64);
            if (quad == 0)
                atomicAdd(&bbp[j * CC + c], val * (1.0f / BB));
        }
    }
}

// ---------------------------------------------------------------------------
extern "C" void kernel_launch(void* const* d_in, const int* in_sizes, int n_in,
                              void* d_out, int out_size, void* d_ws, size_t ws_size,
                              hipStream_t stream) {
    const float* x = (const float*)d_in[0];
    const float* W = (const float*)d_in[1];
    if (in_sizes[0] == CC * JJ * SS * UU) {  // robustness: order by size
        x = (const float*)d_in[1];
        W = (const float*)d_in[0];
    }
    float* out = (float*)d_out;  // fp32 output

    char* ws = (char*)d_ws;
    u16* xA = (u16*)(ws + (16u << 20));         // 4 MiB
    u16* xB = (u16*)(ws + (20u << 20));         // 4 MiB
    u16* Wn = (u16*)(ws + (24u << 20));         // 16 MiB
    float* spart = (float*)(ws + (40u << 20));  // 8 MiB (32 slices)
    size_t b48 = (size_t)48u << 20;
    u16* vB = (u16*)(ws + b48);                 // 128 KiB
    float* bbp = (float*)(ws + b48 + 131072);   // 256 KiB
    float* ccp = (float*)(ws + b48 + 393216);   // 256 KiB

    k_prep<<<2576, 256, 0, stream>>>(x, W, xA, xB, Wn, bbp);

    for (int it = 0; it < 3; ++it) {
        if (it > 0) k_softmax<<<32, 256, 0, stream>>>(bbp, ccp);
        k_gemmA<<<512, 256, 0, stream>>>(xA, Wn, ccp, it > 0 ? 1 : 0, spart);
        k_rsq<<<128, 512, 0, stream>>>(spart, vB, out,
                                       it == 0 ? (1.0f / 2048.0f) : 1.0f,
                                       it == 2 ? 1 : 0);
        if (it < 2) k_gemmBf<<<2048, 256, 0, stream>>>(vB, xB, Wn, bbp);
    }
}